// Round 2
// baseline (630.687 us; speedup 1.0000x reference)
//
#include <hip/hip_runtime.h>
#include <math.h>

#define DIM 128
#define TR 32          // nodes per fused block
#define SAF_STRIDE 132 // fp32 words per sA row (128 + 4 skew: conflict-free ds_add, cheap ds_read_b128)
#define SRC_BITS 25
#define SRC_MASK ((1 << SRC_BITS) - 1)

typedef __attribute__((ext_vector_type(8))) short bf16x8;
typedef __attribute__((ext_vector_type(4))) float f32x4;

__device__ __forceinline__ ushort f2bf(float f) {
    union { float f; unsigned u; } v; v.f = f;
    unsigned u = v.u;
    return (ushort)((u + 0x7FFFu + ((u >> 16) & 1u)) >> 16);  // RNE
}

__global__ void fill_zero(float* p, int n) {
    int i = blockIdx.x * blockDim.x + threadIdx.x;
    if (i < n) p[i] = 0.f;
}

__global__ void fill_zero4(float4* p, int n4) {
    int i = blockIdx.x * blockDim.x + threadIdx.x;
    if (i < n4) p[i] = make_float4(0.f, 0.f, 0.f, 0.f);
}

// Fused init: Wt[n][k] = bf16(W[k][n]); zero deg+cnt (contiguous 2N floats); reset gctr.
__global__ void init_kernel(const float* __restrict__ W, ushort* __restrict__ Wt,
                            float* __restrict__ zbase, int nz, int* __restrict__ gctr) {
    int i = blockIdx.x * blockDim.x + threadIdx.x;
    if (i < 16384) {
        int k = i >> 7, n = i & 127;
        Wt[n * DIM + k] = f2bf(W[k * DIM + n]);
    }
    int z = i - 16384;
    if (z >= 0 && z < nz) zbase[z] = 0.f;
    if (i == 0) *gctr = 0;
}

// cnt[col]++ ; deg[col] += ew[e]
__global__ void count_deg_kernel(const int* __restrict__ ei, const float* __restrict__ ew,
                                 int* __restrict__ cnt, float* __restrict__ deg, int E) {
    int e = blockIdx.x * blockDim.x + threadIdx.x;
    if (e < E) {
        int col = ei[E + e];
        atomicAdd(&cnt[col], 1);
        atomicAdd(&deg[col], ew[e]);
    }
}

// Segment allocation without a global scan: wave-level inclusive scan of cnt,
// one atomicAdd per wave on gctr for the base. Nodes within a wave (64
// consecutive ids) get CONTIGUOUS, ORDERED segments — so any aligned 32-node
// range is one contiguous csr range (the fused kernel's edge-parallel loop
// relies on this). Also fuses deg -> dinv.
__global__ __launch_bounds__(256) void alloc_kernel(const int* __restrict__ cnt,
                                                    float* __restrict__ deg,
                                                    int* __restrict__ row_start,
                                                    int* __restrict__ cursor,
                                                    int* __restrict__ gctr, int N) {
    int i = blockIdx.x * 256 + threadIdx.x;
    int lane = threadIdx.x & 63;
    int c = (i < N) ? cnt[i] : 0;
    int pre = c;
#pragma unroll
    for (int off = 1; off < 64; off <<= 1) {
        int v = __shfl_up(pre, off);
        if (lane >= off) pre += v;
    }
    int tot = __shfl(pre, 63);      // wave total
    int base = 0;
    if (lane == 0) base = atomicAdd(gctr, tot);
    base = __shfl(base, 0);
    if (i < N) {
        int rs = base + pre - c;    // exclusive prefix within wave + wave base
        row_start[i] = rs;
        cursor[i] = rs;
        float d = deg[i];
        deg[i] = d > 0.f ? rsqrtf(d) : 0.f;
    }
}

// CSR fill (packed 8B): p = cursor[col]++;
// csr[p] = { src_row | (local_target << SRC_BITS), bits(dinv[row]*ew*dinv[col]) }
// local_target = col & 31 (blocks of the fused kernel cover 32-aligned node ranges).
__global__ void csr_fill_kernel(const int* __restrict__ ei, const float* __restrict__ ew,
                                const float* __restrict__ dinv, int* __restrict__ cursor,
                                int2* __restrict__ csr, int E) {
    int e = blockIdx.x * blockDim.x + threadIdx.x;
    if (e < E) {
        int row = ei[e];
        int col = ei[E + e];
        int p = atomicAdd(&cursor[col], 1);
        float w = dinv[row] * ew[e] * dinv[col];
        csr[p] = make_int2(row | ((col & (TR - 1)) << SRC_BITS), __float_as_int(w));
    }
}

// Fused: edge-parallel CSR gather -> LDS fp32 atomic tile -> bf16 MFMA 32x128 @ 128x128
// -> bias+LN+GELU+residual.
// 256 threads = 4 waves = 8 gather groups of 32 lanes.
// Phase A (edge-parallel): the block's 32 nodes own ONE contiguous csr range [S,T).
// Group g processes edges j = S + g + 8*it. Per edge: 4 strided x dwords
// (lane l -> cols l, l+32, l+64, l+96; conflict-free ds_add banks) accumulated
// into a fp32 LDS tile via atomicAdd (ds_add_f32). No predication waste, trip
// count balanced across groups, unroll-4 keeps 4 independent csr->x chains in
// flight per group.
// Phase B: convert tile rows to bf16 fragments in-register, MFMA as before.
__global__ __launch_bounds__(256) void gather_mfma_ln_kernel(
        const int2* __restrict__ csr, const int* __restrict__ row_start,
        const int* __restrict__ seg_end, const float* __restrict__ x,
        const ushort* __restrict__ Wt, const float* __restrict__ b,
        const float* __restrict__ gamma, const float* __restrict__ beta,
        float* __restrict__ out, int N) {
    __shared__ __align__(16) float sAf[TR * SAF_STRIDE];  // 16.9 KB fp32 agg tile
    __shared__ float redS[4][16];
    __shared__ float redQ[4][16];

    const int tid  = threadIdx.x;
    const int l32  = tid & 31;
    const int g32  = tid >> 5;       // gather group 0..7
    const int lane = tid & 63;
    const int w    = tid >> 6;       // wave 0..3
    const int row0 = blockIdx.x * TR;

    // ---- zero the accumulation tile ----
    {
        float4* z = (float4*)sAf;
#pragma unroll
        for (int i = 0; i < 5; ++i) {
            int idx = tid + i * 256;
            if (idx < TR * SAF_STRIDE / 4) z[idx] = make_float4(0.f, 0.f, 0.f, 0.f);
        }
    }
    int lastNode = row0 + TR - 1; if (lastNode > N - 1) lastNode = N - 1;
    const int S = row_start[row0];
    const int T = seg_end[lastNode];
    __syncthreads();

    // ---- Phase A: edge-parallel gather ----
    const int M = T - S;
    const int itMax = (M - g32 + 7) >> 3;   // group-uniform; every iteration is a valid edge
    int j = S + g32;
#pragma unroll 4
    for (int it = 0; it < itMax; ++it, j += 8) {
        int2 pk = csr[j];                               // group-uniform 8B load
        float wt = __int_as_float(pk.y);
        int src = pk.x & SRC_MASK;
        int tl  = (int)(((unsigned)pk.x) >> SRC_BITS);  // local target node 0..31
        const float* xr = x + (size_t)src * DIM + l32;
        float a0 = xr[0], a1 = xr[32], a2 = xr[64], a3 = xr[96];
        float* dst = &sAf[tl * SAF_STRIDE + l32];
        atomicAdd(dst +  0, wt * a0);                   // ds_add_f32, 2 lanes/bank (free)
        atomicAdd(dst + 32, wt * a1);
        atomicAdd(dst + 64, wt * a2);
        atomicAdd(dst + 96, wt * a3);
    }
    __syncthreads();

    // ---- Phase B: MFMA GEMM ----
    const int m16  = lane & 15;
    const int quad = lane >> 4;          // 0..3
    const int tm   = w & 1;              // row-tile
    const int tnb  = (w >> 1) * 4;       // first col-tile

    bf16x8 afrag[4];
    const float* arow = &sAf[(16 * tm + m16) * SAF_STRIDE + quad * 8];
#pragma unroll
    for (int kb = 0; kb < 4; ++kb) {
        f32x4 lo = *(const f32x4*)(arow + kb * 32);      // ds_read_b128
        f32x4 hi = *(const f32x4*)(arow + kb * 32 + 4);  // ds_read_b128
        bf16x8 f;
#pragma unroll
        for (int i = 0; i < 4; ++i) {
            f[i]     = (short)f2bf(lo[i]);
            f[i + 4] = (short)f2bf(hi[i]);
        }
        afrag[kb] = f;
    }

    f32x4 acc[4];
#pragma unroll
    for (int t = 0; t < 4; ++t) { acc[t][0] = 0.f; acc[t][1] = 0.f; acc[t][2] = 0.f; acc[t][3] = 0.f; }

#pragma unroll
    for (int kb = 0; kb < 4; ++kb) {
#pragma unroll
        for (int t = 0; t < 4; ++t) {
            const ushort* bp = Wt + (size_t)((tnb + t) * 16 + m16) * DIM + kb * 32 + quad * 8;
            bf16x8 bfrag = *(const bf16x8*)bp;          // global 16B, L1-resident
            acc[t] = __builtin_amdgcn_mfma_f32_16x16x32_bf16(afrag[kb], bfrag, acc[t], 0, 0, 0);
        }
    }

    // ---- bias (per col) before LN stats ----
    float gcol[4], becol[4];
#pragma unroll
    for (int t = 0; t < 4; ++t) {
        int col = (tnb + t) * 16 + m16;
        float bc = b[col];
        gcol[t]  = gamma[col];
        becol[t] = beta[col];
#pragma unroll
        for (int i = 0; i < 4; ++i) acc[t][i] += bc;
    }

    // ---- LN stats: rows 4*quad+i; reduce over this wave's 64 cols via quad shuffles ----
    float s[4], sq[4];
#pragma unroll
    for (int i = 0; i < 4; ++i) {
        s[i]  = acc[0][i] + acc[1][i] + acc[2][i] + acc[3][i];
        sq[i] = acc[0][i]*acc[0][i] + acc[1][i]*acc[1][i] + acc[2][i]*acc[2][i] + acc[3][i]*acc[3][i];
    }
#pragma unroll
    for (int off = 1; off <= 8; off <<= 1) {
#pragma unroll
        for (int i = 0; i < 4; ++i) {
            s[i]  += __shfl_xor(s[i], off);
            sq[i] += __shfl_xor(sq[i], off);
        }
    }
    if (m16 == 0) {
#pragma unroll
        for (int i = 0; i < 4; ++i) {
            redS[w][quad * 4 + i] = s[i];
            redQ[w][quad * 4 + i] = sq[i];
        }
    }
    __syncthreads();

    // ---- finish LN + GELU + residual, store ----
#pragma unroll
    for (int i = 0; i < 4; ++i) {
        int rloc = quad * 4 + i;
        float tot  = redS[w][rloc] + redS[w ^ 2][rloc];   // partner wave shares tm
        float totq = redQ[w][rloc] + redQ[w ^ 2][rloc];
        float mu   = tot * (1.0f / DIM);
        float var  = totq * (1.0f / DIM) - mu * mu;
        float rstd = rsqrtf(var + 1e-5f);
        int r = row0 + 16 * tm + rloc;
        if (r < N) {
#pragma unroll
            for (int t = 0; t < 4; ++t) {
                int col = (tnb + t) * 16 + m16;
                float l = (acc[t][i] - mu) * rstd * gcol[t] + becol[t];
                float g = 0.5f * l * (1.0f + erff(l * 0.70710678118654752f));
                out[(size_t)r * DIM + col] = x[(size_t)r * DIM + col] + g;
            }
        }
    }
}

// ---------------- fallback path (small workspace): atomic scatter + fp32 gemm_ln ----------------
__global__ void deg_kernel(const int* __restrict__ ei, const float* __restrict__ ew,
                           float* __restrict__ deg, int E) {
    int e = blockIdx.x * blockDim.x + threadIdx.x;
    if (e < E) atomicAdd(&deg[ei[E + e]], ew[e]);
}

__global__ void dinv_kernel(float* deg, int N) {
    int i = blockIdx.x * blockDim.x + threadIdx.x;
    if (i < N) {
        float d = deg[i];
        deg[i] = d > 0.f ? rsqrtf(d) : 0.f;
    }
}

__global__ void scatter_kernel(const int* __restrict__ ei, const float* __restrict__ ew,
                               const float* __restrict__ dinv, const float* __restrict__ x,
                               float* __restrict__ out, int E) {
    int t = blockIdx.x * blockDim.x + threadIdx.x;
    int e = t >> 5;
    if (e >= E) return;
    int lane = t & 31;
    int row = ei[e];
    int col = ei[E + e];
    float w = dinv[row] * ew[e] * dinv[col];
    float4 v = *(const float4*)(x + (size_t)row * DIM + (lane << 2));
    float* dst = out + (size_t)col * DIM + (lane << 2);
    atomicAdd(dst + 0, v.x * w);
    atomicAdd(dst + 1, v.y * w);
    atomicAdd(dst + 2, v.z * w);
    atomicAdd(dst + 3, v.w * w);
}

__global__ __launch_bounds__(256) void gemm_ln_kernel(const float* __restrict__ x,
                                                      const float* __restrict__ W,
                                                      const float* __restrict__ b,
                                                      const float* __restrict__ gamma,
                                                      const float* __restrict__ beta,
                                                      float* __restrict__ out, int N) {
    __shared__ float sT[DIM][TR + 4];
    const int tid = threadIdx.x;
    const int row0 = blockIdx.x * TR;
    {
        int r = tid >> 3;
        int c0 = (tid & 7) << 4;
        int rr = row0 + r; if (rr > N - 1) rr = N - 1;
        const float4* src = (const float4*)(out + (size_t)rr * DIM + c0);
#pragma unroll
        for (int i = 0; i < 4; ++i) {
            float4 v = src[i];
            int c = c0 + i * 4;
            sT[c + 0][r] = v.x; sT[c + 1][r] = v.y; sT[c + 2][r] = v.z; sT[c + 3][r] = v.w;
        }
    }
    __syncthreads();
    const int tx = tid & 31;
    const int ty = tid >> 5;
    float acc[4][4] = {};
    const float4* Wv = (const float4*)W;
#pragma unroll 4
    for (int k = 0; k < DIM; ++k) {
        float4 wv = Wv[k * 32 + tx];
        float4 a  = *(const float4*)(&sT[k][ty * 4]);
        acc[0][0] += a.x * wv.x; acc[0][1] += a.x * wv.y; acc[0][2] += a.x * wv.z; acc[0][3] += a.x * wv.w;
        acc[1][0] += a.y * wv.x; acc[1][1] += a.y * wv.y; acc[1][2] += a.y * wv.z; acc[1][3] += a.y * wv.w;
        acc[2][0] += a.z * wv.x; acc[2][1] += a.z * wv.y; acc[2][2] += a.z * wv.z; acc[2][3] += a.z * wv.w;
        acc[3][0] += a.w * wv.x; acc[3][1] += a.w * wv.y; acc[3][2] += a.w * wv.z; acc[3][3] += a.w * wv.w;
    }
    float4 b4 = ((const float4*)b)[tx];
#pragma unroll
    for (int i = 0; i < 4; ++i) {
        acc[i][0] += b4.x; acc[i][1] += b4.y; acc[i][2] += b4.z; acc[i][3] += b4.w;
    }
    float4 g4  = ((const float4*)gamma)[tx];
    float4 be4 = ((const float4*)beta)[tx];
#pragma unroll
    for (int i = 0; i < 4; ++i) {
        float s  = acc[i][0] + acc[i][1] + acc[i][2] + acc[i][3];
        float sq = acc[i][0]*acc[i][0] + acc[i][1]*acc[i][1] + acc[i][2]*acc[i][2] + acc[i][3]*acc[i][3];
#pragma unroll
        for (int off = 16; off > 0; off >>= 1) {
            s  += __shfl_xor(s, off);
            sq += __shfl_xor(sq, off);
        }
        float mu   = s * (1.0f / DIM);
        float var  = sq * (1.0f / DIM) - mu * mu;
        float rstd = rsqrtf(var + 1e-5f);
        int r = row0 + ty * 4 + i;
        if (r < N) {
            float4 xr = *(const float4*)(x + (size_t)r * DIM + tx * 4);
            float lg[4] = {g4.x, g4.y, g4.z, g4.w};
            float lb[4] = {be4.x, be4.y, be4.z, be4.w};
            float lx[4] = {xr.x, xr.y, xr.z, xr.w};
            float o[4];
#pragma unroll
            for (int c = 0; c < 4; ++c) {
                float l = (acc[i][c] - mu) * rstd * lg[c] + lb[c];
                float g = 0.5f * l * (1.0f + erff(l * 0.70710678118654752f));
                o[c] = lx[c] + g;
            }
            *(float4*)(out + (size_t)r * DIM + tx * 4) = make_float4(o[0], o[1], o[2], o[3]);
        }
    }
}

extern "C" void kernel_launch(void* const* d_in, const int* in_sizes, int n_in,
                              void* d_out, int out_size, void* d_ws, size_t ws_size,
                              hipStream_t stream) {
    const float* x     = (const float*)d_in[0];
    const int*   ei    = (const int*)d_in[1];    // [2, E] int32
    const float* ew    = (const float*)d_in[2];
    const float* W     = (const float*)d_in[3];
    const float* b     = (const float*)d_in[4];
    const float* gamma = (const float*)d_in[5];
    const float* beta  = (const float*)d_in[6];
    const int N = in_sizes[0] / DIM;
    const int E = in_sizes[2];
    float* out = (float*)d_out;

    const int nb = (N + 255) / 256;

    // ws words: Wt bf16[128*128] (8192 words) | deg[N] | cnt[N] | row_start[N] |
    //           cursor[N] | gctr[1] | pad | csr int2[E]
    size_t hdr_words = 8192 + (size_t)4 * N + 2;
    hdr_words = (hdr_words + 1) & ~(size_t)1;
    size_t ws_need = (hdr_words + (size_t)2 * E) * sizeof(float);

    if (ws_size >= ws_need && N <= (1 << SRC_BITS)) {
        ushort* Wt         = (ushort*)d_ws;
        float*  deg        = (float*)d_ws + 8192;
        int*    cnt        = (int*)(deg + N);
        int*    row_start  = cnt + N;
        int*    cursor     = row_start + N;
        int*    gctr       = cursor + N;
        int2*   csr        = (int2*)((float*)d_ws + hdr_words);

        int initn = 16384 + 2 * N;
        init_kernel<<<(initn + 255) / 256, 256, 0, stream>>>(W, Wt, deg, 2 * N, gctr);
        count_deg_kernel<<<(E + 255) / 256, 256, 0, stream>>>(ei, ew, cnt, deg, E);
        alloc_kernel<<<nb, 256, 0, stream>>>(cnt, deg, row_start, cursor, gctr, N);
        csr_fill_kernel<<<(E + 255) / 256, 256, 0, stream>>>(ei, ew, deg, cursor, csr, E);

        gather_mfma_ln_kernel<<<(N + TR - 1) / TR, 256, 0, stream>>>(
            csr, row_start, cursor, x, Wt, b, gamma, beta, out, N);
    } else {
        float* deg = (float*)d_ws;
        int n4 = N * DIM / 4;
        fill_zero4<<<(n4 + 255) / 256, 256, 0, stream>>>((float4*)out, n4);
        fill_zero<<<nb, 256, 0, stream>>>(deg, N);
        deg_kernel<<<(E + 255) / 256, 256, 0, stream>>>(ei, ew, deg, E);
        dinv_kernel<<<nb, 256, 0, stream>>>(deg, N);
        long long sthreads = (long long)E * 32;
        scatter_kernel<<<(int)((sthreads + 255) / 256), 256, 0, stream>>>(ei, ew, deg, x, out, E);
        gemm_ln_kernel<<<(N + TR - 1) / TR, 256, 0, stream>>>(x, W, b, gamma, beta, out, N);
    }
}

// Round 3
// 303.525 us; speedup vs baseline: 2.0779x; 2.0779x over previous
//
#include <hip/hip_runtime.h>
#include <math.h>

#define DIM 128
#define TR 32         // nodes per fused block
#define SA_STRIDE 136 // bf16 elements per sA row (128 + 8 pad, keeps 16B alignment)

typedef __attribute__((ext_vector_type(8))) short bf16x8;
typedef __attribute__((ext_vector_type(4))) float f32x4;

__device__ __forceinline__ ushort f2bf(float f) {
    union { float f; unsigned u; } v; v.f = f;
    unsigned u = v.u;
    return (ushort)((u + 0x7FFFu + ((u >> 16) & 1u)) >> 16);  // RNE
}

__global__ void fill_zero(float* p, int n) {
    int i = blockIdx.x * blockDim.x + threadIdx.x;
    if (i < n) p[i] = 0.f;
}

__global__ void fill_zero4(float4* p, int n4) {
    int i = blockIdx.x * blockDim.x + threadIdx.x;
    if (i < n4) p[i] = make_float4(0.f, 0.f, 0.f, 0.f);
}

// Fused init: Wt[n][k] = bf16(W[k][n]); zero cd pairs (2N words); reset gctr.
__global__ void init_kernel(const float* __restrict__ W, ushort* __restrict__ Wt,
                            float* __restrict__ zbase, int nz, int* __restrict__ gctr) {
    int i = blockIdx.x * blockDim.x + threadIdx.x;
    if (i < 16384) {
        int k = i >> 7, n = i & 127;
        Wt[n * DIM + k] = f2bf(W[k * DIM + n]);
    }
    int z = i - 16384;
    if (z >= 0 && z < nz) zbase[z] = 0.f;
    if (i == 0) *gctr = 0;
}

// cd[col] = {cnt, deg} interleaved: both atomics per edge hit the SAME 64B line.
__global__ void count_deg_kernel(const int* __restrict__ ei, const float* __restrict__ ew,
                                 int* __restrict__ cdi, int E) {
    int e = blockIdx.x * blockDim.x + threadIdx.x;
    if (e < E) {
        int col = ei[E + e];
        atomicAdd(&cdi[2 * col], 1);
        atomicAdd((float*)&cdi[2 * col + 1], ew[e]);
    }
}

// Segment allocation: wave-level inclusive scan of cnt, block-level combine in LDS,
// ONE atomicAdd per BLOCK on gctr (391 hot-address atomics, not 1564 — the per-wave
// version serialized on the cross-XCD hot line). Nodes within a block (256
// consecutive ids) get contiguous, ordered segments, so any aligned 32-node range
// is one contiguous csr range (the fused kernel relies on this).
// Also computes dinv = rsqrt(deg) (deg>0) from the cd pairs.
__global__ __launch_bounds__(256) void alloc_kernel(const int2* __restrict__ cd,
                                                    float* __restrict__ dinv,
                                                    int* __restrict__ row_start,
                                                    int* __restrict__ cursor,
                                                    int* __restrict__ gctr, int N) {
    __shared__ int wsum[4];
    __shared__ int sbase;
    int t = threadIdx.x;
    int i = blockIdx.x * 256 + t;
    int lane = t & 63;
    int w = t >> 6;
    int2 p = (i < N) ? cd[i] : make_int2(0, 0);
    int c = p.x;
    int pre = c;
#pragma unroll
    for (int off = 1; off < 64; off <<= 1) {
        int v = __shfl_up(pre, off);
        if (lane >= off) pre += v;
    }
    if (lane == 63) wsum[w] = pre;
    __syncthreads();
    if (t == 0) sbase = atomicAdd(gctr, wsum[0] + wsum[1] + wsum[2] + wsum[3]);
    __syncthreads();
    int woff = 0;
#pragma unroll
    for (int k = 0; k < 3; ++k) if (w > k) woff += wsum[k];
    if (i < N) {
        int rs = sbase + woff + pre - c;   // exclusive prefix within block + block base
        row_start[i] = rs;
        cursor[i] = rs;
        float d = __int_as_float(p.y);
        dinv[i] = d > 0.f ? rsqrtf(d) : 0.f;
    }
}

// CSR fill (packed 8B): p = cursor[col]++; csr[p] = {row, bits(dinv[row]*ew)}.
// dinv[col] is factored out (applied once per node in the gather kernel), so only
// TWO random lines per edge here (cursor[col], dinv[row]) instead of three.
__global__ void csr_fill_kernel(const int* __restrict__ ei, const float* __restrict__ ew,
                                const float* __restrict__ dinv, int* __restrict__ cursor,
                                int2* __restrict__ csr, int E) {
    int e = blockIdx.x * blockDim.x + threadIdx.x;
    if (e < E) {
        int row = ei[e];
        int col = ei[E + e];
        int p = atomicAdd(&cursor[col], 1);
        float w = dinv[row] * ew[e];
        csr[p] = make_int2(row, __float_as_int(w));
    }
}

// Fused: CSR gather (fp32) -> LDS bf16 -> MFMA 32x128 @ 128x128 -> bias+LN+GELU+residual.
// 256 threads = 4 waves. Gather: 8 groups of 32 lanes, 4 nodes each, ROUND-ROBIN:
// all 4 nodes' edge lists stepped in lockstep, unroll 4 -> 16 independent csr->x
// dependency chains in flight per group (latency-bound phase; MLP is the lever).
// Invalid slots are predicated (clamp to csr[0], weight 0) so loads always issue
// and stay L1-resident. Final accumulator scaled by dinv[node] (factored norm).
// GEMM: wave w -> row-tile tm=w&1 (16 rows), col-tiles tn = 4*(w>>1)..+3 (64 cols).
__global__ __launch_bounds__(256) void gather_mfma_ln_kernel(
        const int2* __restrict__ csr, const int* __restrict__ row_start,
        const int* __restrict__ seg_end, const float* __restrict__ dinv,
        const float* __restrict__ x,
        const ushort* __restrict__ Wt, const float* __restrict__ b,
        const float* __restrict__ gamma, const float* __restrict__ beta,
        float* __restrict__ out, int N) {
    __shared__ ushort sA[TR * SA_STRIDE];  // 8.5 KB bf16 agg tile
    __shared__ float redS[4][16];
    __shared__ float redQ[4][16];

    const int tid  = threadIdx.x;
    const int l32  = tid & 31;
    const int g32  = tid >> 5;       // gather group 0..7
    const int lane = tid & 63;
    const int w    = tid >> 6;       // wave 0..3
    const int row0 = blockIdx.x * TR;

    // ---- Phase A: round-robin gather, 4 nodes per 32-lane group ----
    const float4* xv = (const float4*)x;
    int sidx[4], eidx[4];
    float dv[4];
    float4 accq[4];
    int maxlen = 0;
#pragma unroll
    for (int q = 0; q < 4; ++q) {
        int node = row0 + g32 * 4 + q;
        int ok = node < N;
        sidx[q] = ok ? row_start[node] : 0;
        eidx[q] = ok ? seg_end[node] : 0;
        dv[q]   = ok ? dinv[node] : 0.f;
        accq[q] = make_float4(0.f, 0.f, 0.f, 0.f);
        int len = eidx[q] - sidx[q];
        maxlen = len > maxlen ? len : maxlen;
    }
    // maxlen is group-uniform (node ids are group-uniform)
#pragma unroll 4
    for (int it = 0; it < maxlen; ++it) {
        int2 pk[4];
#pragma unroll
        for (int q = 0; q < 4; ++q) {
            int j = sidx[q] + it;
            pk[q] = csr[j < eidx[q] ? j : 0];   // predicated slot, always-valid addr
        }
#pragma unroll
        for (int q = 0; q < 4; ++q) {
            float wt = (sidx[q] + it < eidx[q]) ? __int_as_float(pk[q].y) : 0.f;
            float4 v = xv[(size_t)pk[q].x * 32 + l32];
            accq[q].x += wt * v.x; accq[q].y += wt * v.y;
            accq[q].z += wt * v.z; accq[q].w += wt * v.w;
        }
    }
#pragma unroll
    for (int q = 0; q < 4; ++q) {
        int r = g32 * 4 + q;
        ushort4 p4;
        p4.x = f2bf(accq[q].x * dv[q]); p4.y = f2bf(accq[q].y * dv[q]);
        p4.z = f2bf(accq[q].z * dv[q]); p4.w = f2bf(accq[q].w * dv[q]);
        *(ushort4*)&sA[r * SA_STRIDE + l32 * 4] = p4;   // ds_write_b64, conflict-free
    }
    __syncthreads();

    // ---- Phase B: MFMA GEMM ----
    const int m16  = lane & 15;
    const int quad = lane >> 4;          // 0..3
    const int tm   = w & 1;              // row-tile
    const int tnb  = (w >> 1) * 4;       // first col-tile

    bf16x8 afrag[4];
    const ushort* arow = &sA[(16 * tm + m16) * SA_STRIDE + quad * 8];
#pragma unroll
    for (int kb = 0; kb < 4; ++kb)
        afrag[kb] = *(const bf16x8*)(arow + kb * 32);   // ds_read_b128

    f32x4 acc[4];
#pragma unroll
    for (int t = 0; t < 4; ++t) { acc[t][0] = 0.f; acc[t][1] = 0.f; acc[t][2] = 0.f; acc[t][3] = 0.f; }

#pragma unroll
    for (int kb = 0; kb < 4; ++kb) {
#pragma unroll
        for (int t = 0; t < 4; ++t) {
            const ushort* bp = Wt + (size_t)((tnb + t) * 16 + m16) * DIM + kb * 32 + quad * 8;
            bf16x8 bfrag = *(const bf16x8*)bp;          // global 16B, L1-resident
            acc[t] = __builtin_amdgcn_mfma_f32_16x16x32_bf16(afrag[kb], bfrag, acc[t], 0, 0, 0);
        }
    }

    // ---- bias (per col) before LN stats ----
    float gcol[4], becol[4];
#pragma unroll
    for (int t = 0; t < 4; ++t) {
        int col = (tnb + t) * 16 + m16;
        float bc = b[col];
        gcol[t]  = gamma[col];
        becol[t] = beta[col];
#pragma unroll
        for (int i = 0; i < 4; ++i) acc[t][i] += bc;
    }

    // ---- LN stats: rows 4*quad+i; reduce over this wave's 64 cols via quad shuffles ----
    float s[4], sq[4];
#pragma unroll
    for (int i = 0; i < 4; ++i) {
        s[i]  = acc[0][i] + acc[1][i] + acc[2][i] + acc[3][i];
        sq[i] = acc[0][i]*acc[0][i] + acc[1][i]*acc[1][i] + acc[2][i]*acc[2][i] + acc[3][i]*acc[3][i];
    }
#pragma unroll
    for (int off = 1; off <= 8; off <<= 1) {
#pragma unroll
        for (int i = 0; i < 4; ++i) {
            s[i]  += __shfl_xor(s[i], off);
            sq[i] += __shfl_xor(sq[i], off);
        }
    }
    if (m16 == 0) {
#pragma unroll
        for (int i = 0; i < 4; ++i) {
            redS[w][quad * 4 + i] = s[i];
            redQ[w][quad * 4 + i] = sq[i];
        }
    }
    __syncthreads();

    // ---- finish LN + GELU + residual, store ----
#pragma unroll
    for (int i = 0; i < 4; ++i) {
        int rloc = quad * 4 + i;
        float tot  = redS[w][rloc] + redS[w ^ 2][rloc];   // partner wave shares tm
        float totq = redQ[w][rloc] + redQ[w ^ 2][rloc];
        float mu   = tot * (1.0f / DIM);
        float var  = totq * (1.0f / DIM) - mu * mu;
        float rstd = rsqrtf(var + 1e-5f);
        int r = row0 + 16 * tm + rloc;
        if (r < N) {
#pragma unroll
            for (int t = 0; t < 4; ++t) {
                int col = (tnb + t) * 16 + m16;
                float l = (acc[t][i] - mu) * rstd * gcol[t] + becol[t];
                float g = 0.5f * l * (1.0f + erff(l * 0.70710678118654752f));
                out[(size_t)r * DIM + col] = x[(size_t)r * DIM + col] + g;
            }
        }
    }
}

// ---------------- fallback path (small workspace): atomic scatter + fp32 gemm_ln ----------------
__global__ void deg_kernel(const int* __restrict__ ei, const float* __restrict__ ew,
                           float* __restrict__ deg, int E) {
    int e = blockIdx.x * blockDim.x + threadIdx.x;
    if (e < E) atomicAdd(&deg[ei[E + e]], ew[e]);
}

__global__ void dinv_kernel(float* deg, int N) {
    int i = blockIdx.x * blockDim.x + threadIdx.x;
    if (i < N) {
        float d = deg[i];
        deg[i] = d > 0.f ? rsqrtf(d) : 0.f;
    }
}

__global__ void scatter_kernel(const int* __restrict__ ei, const float* __restrict__ ew,
                               const float* __restrict__ dinv, const float* __restrict__ x,
                               float* __restrict__ out, int E) {
    int t = blockIdx.x * blockDim.x + threadIdx.x;
    int e = t >> 5;
    if (e >= E) return;
    int lane = t & 31;
    int row = ei[e];
    int col = ei[E + e];
    float w = dinv[row] * ew[e] * dinv[col];
    float4 v = *(const float4*)(x + (size_t)row * DIM + (lane << 2));
    float* dst = out + (size_t)col * DIM + (lane << 2);
    atomicAdd(dst + 0, v.x * w);
    atomicAdd(dst + 1, v.y * w);
    atomicAdd(dst + 2, v.z * w);
    atomicAdd(dst + 3, v.w * w);
}

__global__ __launch_bounds__(256) void gemm_ln_kernel(const float* __restrict__ x,
                                                      const float* __restrict__ W,
                                                      const float* __restrict__ b,
                                                      const float* __restrict__ gamma,
                                                      const float* __restrict__ beta,
                                                      float* __restrict__ out, int N) {
    __shared__ float sT[DIM][TR + 4];
    const int tid = threadIdx.x;
    const int row0 = blockIdx.x * TR;
    {
        int r = tid >> 3;
        int c0 = (tid & 7) << 4;
        int rr = row0 + r; if (rr > N - 1) rr = N - 1;
        const float4* src = (const float4*)(out + (size_t)rr * DIM + c0);
#pragma unroll
        for (int i = 0; i < 4; ++i) {
            float4 v = src[i];
            int c = c0 + i * 4;
            sT[c + 0][r] = v.x; sT[c + 1][r] = v.y; sT[c + 2][r] = v.z; sT[c + 3][r] = v.w;
        }
    }
    __syncthreads();
    const int tx = tid & 31;
    const int ty = tid >> 5;
    float acc[4][4] = {};
    const float4* Wv = (const float4*)W;
#pragma unroll 4
    for (int k = 0; k < DIM; ++k) {
        float4 wv = Wv[k * 32 + tx];
        float4 a  = *(const float4*)(&sT[k][ty * 4]);
        acc[0][0] += a.x * wv.x; acc[0][1] += a.x * wv.y; acc[0][2] += a.x * wv.z; acc[0][3] += a.x * wv.w;
        acc[1][0] += a.y * wv.x; acc[1][1] += a.y * wv.y; acc[1][2] += a.y * wv.z; acc[1][3] += a.y * wv.w;
        acc[2][0] += a.z * wv.x; acc[2][1] += a.z * wv.y; acc[2][2] += a.z * wv.z; acc[2][3] += a.z * wv.w;
        acc[3][0] += a.w * wv.x; acc[3][1] += a.w * wv.y; acc[3][2] += a.w * wv.z; acc[3][3] += a.w * wv.w;
    }
    float4 b4 = ((const float4*)b)[tx];
#pragma unroll
    for (int i = 0; i < 4; ++i) {
        acc[i][0] += b4.x; acc[i][1] += b4.y; acc[i][2] += b4.z; acc[i][3] += b4.w;
    }
    float4 g4  = ((const float4*)gamma)[tx];
    float4 be4 = ((const float4*)beta)[tx];
#pragma unroll
    for (int i = 0; i < 4; ++i) {
        float s  = acc[i][0] + acc[i][1] + acc[i][2] + acc[i][3];
        float sq = acc[i][0]*acc[i][0] + acc[i][1]*acc[i][1] + acc[i][2]*acc[i][2] + acc[i][3]*acc[i][3];
#pragma unroll
        for (int off = 16; off > 0; off >>= 1) {
            s  += __shfl_xor(s, off);
            sq += __shfl_xor(sq, off);
        }
        float mu   = s * (1.0f / DIM);
        float var  = sq * (1.0f / DIM) - mu * mu;
        float rstd = rsqrtf(var + 1e-5f);
        int r = row0 + ty * 4 + i;
        if (r < N) {
            float4 xr = *(const float4*)(x + (size_t)r * DIM + tx * 4);
            float lg[4] = {g4.x, g4.y, g4.z, g4.w};
            float lb[4] = {be4.x, be4.y, be4.z, be4.w};
            float lx[4] = {xr.x, xr.y, xr.z, xr.w};
            float o[4];
#pragma unroll
            for (int c = 0; c < 4; ++c) {
                float l = (acc[i][c] - mu) * rstd * lg[c] + lb[c];
                float g = 0.5f * l * (1.0f + erff(l * 0.70710678118654752f));
                o[c] = lx[c] + g;
            }
            *(float4*)(out + (size_t)r * DIM + tx * 4) = make_float4(o[0], o[1], o[2], o[3]);
        }
    }
}

extern "C" void kernel_launch(void* const* d_in, const int* in_sizes, int n_in,
                              void* d_out, int out_size, void* d_ws, size_t ws_size,
                              hipStream_t stream) {
    const float* x     = (const float*)d_in[0];
    const int*   ei    = (const int*)d_in[1];    // [2, E] int32
    const float* ew    = (const float*)d_in[2];
    const float* W     = (const float*)d_in[3];
    const float* b     = (const float*)d_in[4];
    const float* gamma = (const float*)d_in[5];
    const float* beta  = (const float*)d_in[6];
    const int N = in_sizes[0] / DIM;
    const int E = in_sizes[2];
    float* out = (float*)d_out;

    const int nb = (N + 255) / 256;

    // ws words: Wt bf16[128*128] (8192 words) | cd int2[N] (2N) | dinv[N] |
    //           row_start[N] | cursor[N] | gctr[1] | pad | csr int2[E]
    size_t hdr_words = 8192 + (size_t)5 * N + 2;
    hdr_words = (hdr_words + 1) & ~(size_t)1;
    size_t ws_need = (hdr_words + (size_t)2 * E) * sizeof(float);

    if (ws_size >= ws_need) {
        ushort* Wt         = (ushort*)d_ws;
        int2*   cd         = (int2*)((float*)d_ws + 8192);
        float*  dinv       = (float*)d_ws + 8192 + (size_t)2 * N;
        int*    row_start  = (int*)(dinv + N);
        int*    cursor     = row_start + N;
        int*    gctr       = cursor + N;
        int2*   csr        = (int2*)((float*)d_ws + hdr_words);

        int initn = 16384 + 2 * N;
        init_kernel<<<(initn + 255) / 256, 256, 0, stream>>>(W, Wt, (float*)cd, 2 * N, gctr);
        count_deg_kernel<<<(E + 255) / 256, 256, 0, stream>>>(ei, ew, (int*)cd, E);
        alloc_kernel<<<nb, 256, 0, stream>>>(cd, dinv, row_start, cursor, gctr, N);
        csr_fill_kernel<<<(E + 255) / 256, 256, 0, stream>>>(ei, ew, dinv, cursor, csr, E);

        gather_mfma_ln_kernel<<<(N + TR - 1) / TR, 256, 0, stream>>>(
            csr, row_start, cursor, dinv, x, Wt, b, gamma, beta, out, N);
    } else {
        float* deg = (float*)d_ws;
        int n4 = N * DIM / 4;
        fill_zero4<<<(n4 + 255) / 256, 256, 0, stream>>>((float4*)out, n4);
        fill_zero<<<nb, 256, 0, stream>>>(deg, N);
        deg_kernel<<<(E + 255) / 256, 256, 0, stream>>>(ei, ew, deg, E);
        dinv_kernel<<<nb, 256, 0, stream>>>(deg, N);
        long long sthreads = (long long)E * 32;
        scatter_kernel<<<(int)((sthreads + 255) / 256), 256, 0, stream>>>(ei, ew, deg, x, out, E);
        gemm_ln_kernel<<<(N + TR - 1) / TR, 256, 0, stream>>>(x, W, b, gamma, beta, out, N);
    }
}

// Round 4
// 261.348 us; speedup vs baseline: 2.4132x; 1.1614x over previous
//
#include <hip/hip_runtime.h>
#include <math.h>

#define DIM 128
#define TR 32         // nodes per fused block
#define SA_STRIDE 136 // bf16 elements per sA row (128 + 8 pad, keeps 16B alignment)

#define DEG_SHIFT 42          // cnt in bits 42..63 of packed u64
#define DEG_SCALE 33554432.0f // 2^25 fixed-point scale for deg
#define DEG_MASK ((1ull << DEG_SHIFT) - 1)

typedef __attribute__((ext_vector_type(8))) short bf16x8;
typedef __attribute__((ext_vector_type(4))) float f32x4;

__device__ __forceinline__ ushort f2bf(float f) {
    union { float f; unsigned u; } v; v.f = f;
    unsigned u = v.u;
    return (ushort)((u + 0x7FFFu + ((u >> 16) & 1u)) >> 16);  // RNE
}

__global__ void fill_zero(float* p, int n) {
    int i = blockIdx.x * blockDim.x + threadIdx.x;
    if (i < n) p[i] = 0.f;
}

__global__ void fill_zero4(float4* p, int n4) {
    int i = blockIdx.x * blockDim.x + threadIdx.x;
    if (i < n4) p[i] = make_float4(0.f, 0.f, 0.f, 0.f);
}

// Fused init: Wt[n][k] = bf16(W[k][n]); zero cd (2N words); reset gctr.
__global__ void init_kernel(const float* __restrict__ W, ushort* __restrict__ Wt,
                            float* __restrict__ zbase, int nz, int* __restrict__ gctr) {
    int i = blockIdx.x * blockDim.x + threadIdx.x;
    if (i < 16384) {
        int k = i >> 7, n = i & 127;
        Wt[n * DIM + k] = f2bf(W[k * DIM + n]);
    }
    int z = i - 16384;
    if (z >= 0 && z < nz) zbase[z] = 0.f;
    if (i == 0) *gctr = 0;
}

// ONE u64 atomic per edge: cd[col] += (1<<42) | round(ew * 2^25).
// cnt in the high bits, fixed-point deg in the low bits (deg sum << 2^42/2^25
// headroom; per-edge rounding error ~2^-26 — invisible under bf16 rounding).
__global__ void count_deg_kernel(const int* __restrict__ ei, const float* __restrict__ ew,
                                 unsigned long long* __restrict__ cd, int E) {
    int e = blockIdx.x * blockDim.x + threadIdx.x;
    if (e < E) {
        int col = ei[E + e];
        unsigned long long pk = (1ull << DEG_SHIFT)
                              + (unsigned long long)(ew[e] * DEG_SCALE + 0.5f);
        atomicAdd(&cd[col], pk);
    }
}

// Segment allocation: wave-level inclusive scan of cnt, block-level combine in LDS,
// ONE atomicAdd per BLOCK on gctr (391 hot-address atomics — per-wave serialized
// on the cross-XCD hot line). Nodes within a block (256 consecutive ids) get
// contiguous, ordered segments, so any aligned 32-node range is one contiguous
// csr range (the fused kernel relies on this). Also computes dinv from packed deg.
__global__ __launch_bounds__(256) void alloc_kernel(const unsigned long long* __restrict__ cd,
                                                    float* __restrict__ dinv,
                                                    int* __restrict__ row_start,
                                                    int* __restrict__ cursor,
                                                    int* __restrict__ gctr, int N) {
    __shared__ int wsum[4];
    __shared__ int sbase;
    int t = threadIdx.x;
    int i = blockIdx.x * 256 + t;
    int lane = t & 63;
    int w = t >> 6;
    unsigned long long p = (i < N) ? cd[i] : 0ull;
    int c = (int)(p >> DEG_SHIFT);
    int pre = c;
#pragma unroll
    for (int off = 1; off < 64; off <<= 1) {
        int v = __shfl_up(pre, off);
        if (lane >= off) pre += v;
    }
    if (lane == 63) wsum[w] = pre;
    __syncthreads();
    if (t == 0) sbase = atomicAdd(gctr, wsum[0] + wsum[1] + wsum[2] + wsum[3]);
    __syncthreads();
    int woff = 0;
#pragma unroll
    for (int k = 0; k < 3; ++k) if (w > k) woff += wsum[k];
    if (i < N) {
        int rs = sbase + woff + pre - c;   // exclusive prefix within block + block base
        row_start[i] = rs;
        cursor[i] = rs;
        float d = (float)(p & DEG_MASK) * (1.0f / DEG_SCALE);
        dinv[i] = d > 0.f ? rsqrtf(d) : 0.f;
    }
}

// CSR fill (packed 8B): p = cursor[col]++; csr[p] = {row, bits(dinv[row]*ew)}.
// dinv[col] is factored out (applied once per node in the gather kernel), so only
// TWO random lines per edge here (cursor[col], dinv[row]) instead of three.
__global__ void csr_fill_kernel(const int* __restrict__ ei, const float* __restrict__ ew,
                                const float* __restrict__ dinv, int* __restrict__ cursor,
                                int2* __restrict__ csr, int E) {
    int e = blockIdx.x * blockDim.x + threadIdx.x;
    if (e < E) {
        int row = ei[e];
        int col = ei[E + e];
        int p = atomicAdd(&cursor[col], 1);
        float w = dinv[row] * ew[e];
        csr[p] = make_int2(row, __float_as_int(w));
    }
}

// Fused: CSR gather (fp32) -> LDS bf16 -> MFMA 32x128 @ 128x128 -> bias+LN+GELU+residual.
// 256 threads = 4 waves. Gather: 8 groups of 32 lanes, 4 nodes each, ROUND-ROBIN:
// all 4 nodes' edge lists stepped in lockstep, unroll 2 -> 8 independent csr->x
// dependency chains in flight per group. unroll 4 was tried and REGRESSED
// (VGPR 44->72, occupancy 46%->30%, 96->125 us): TLP hides more than the extra
// ILP adds — keep VGPR under the occupancy cliff. Invalid slots are predicated
// (clamp to csr[0], weight 0) so loads always issue and stay L1-resident.
// Final accumulator scaled by dinv[node] (factored norm).
// GEMM: wave w -> row-tile tm=w&1 (16 rows), col-tiles tn = 4*(w>>1)..+3 (64 cols).
__global__ __launch_bounds__(256) void gather_mfma_ln_kernel(
        const int2* __restrict__ csr, const int* __restrict__ row_start,
        const int* __restrict__ seg_end, const float* __restrict__ dinv,
        const float* __restrict__ x,
        const ushort* __restrict__ Wt, const float* __restrict__ b,
        const float* __restrict__ gamma, const float* __restrict__ beta,
        float* __restrict__ out, int N) {
    __shared__ ushort sA[TR * SA_STRIDE];  // 8.5 KB bf16 agg tile
    __shared__ float redS[4][16];
    __shared__ float redQ[4][16];

    const int tid  = threadIdx.x;
    const int l32  = tid & 31;
    const int g32  = tid >> 5;       // gather group 0..7
    const int lane = tid & 63;
    const int w    = tid >> 6;       // wave 0..3
    const int row0 = blockIdx.x * TR;

    // ---- Phase A: round-robin gather, 4 nodes per 32-lane group ----
    const float4* xv = (const float4*)x;
    int sidx[4], eidx[4];
    float dv[4];
    float4 accq[4];
    int maxlen = 0;
#pragma unroll
    for (int q = 0; q < 4; ++q) {
        int node = row0 + g32 * 4 + q;
        int ok = node < N;
        sidx[q] = ok ? row_start[node] : 0;
        eidx[q] = ok ? seg_end[node] : 0;
        dv[q]   = ok ? dinv[node] : 0.f;
        accq[q] = make_float4(0.f, 0.f, 0.f, 0.f);
        int len = eidx[q] - sidx[q];
        maxlen = len > maxlen ? len : maxlen;
    }
    // maxlen is group-uniform (node ids are group-uniform)
#pragma unroll 2
    for (int it = 0; it < maxlen; ++it) {
        int2 pk[4];
#pragma unroll
        for (int q = 0; q < 4; ++q) {
            int j = sidx[q] + it;
            pk[q] = csr[j < eidx[q] ? j : 0];   // predicated slot, always-valid addr
        }
#pragma unroll
        for (int q = 0; q < 4; ++q) {
            float wt = (sidx[q] + it < eidx[q]) ? __int_as_float(pk[q].y) : 0.f;
            float4 v = xv[(size_t)pk[q].x * 32 + l32];
            accq[q].x += wt * v.x; accq[q].y += wt * v.y;
            accq[q].z += wt * v.z; accq[q].w += wt * v.w;
        }
    }
#pragma unroll
    for (int q = 0; q < 4; ++q) {
        int r = g32 * 4 + q;
        ushort4 p4;
        p4.x = f2bf(accq[q].x * dv[q]); p4.y = f2bf(accq[q].y * dv[q]);
        p4.z = f2bf(accq[q].z * dv[q]); p4.w = f2bf(accq[q].w * dv[q]);
        *(ushort4*)&sA[r * SA_STRIDE + l32 * 4] = p4;   // ds_write_b64, conflict-free
    }
    __syncthreads();

    // ---- Phase B: MFMA GEMM ----
    const int m16  = lane & 15;
    const int quad = lane >> 4;          // 0..3
    const int tm   = w & 1;              // row-tile
    const int tnb  = (w >> 1) * 4;       // first col-tile

    bf16x8 afrag[4];
    const ushort* arow = &sA[(16 * tm + m16) * SA_STRIDE + quad * 8];
#pragma unroll
    for (int kb = 0; kb < 4; ++kb)
        afrag[kb] = *(const bf16x8*)(arow + kb * 32);   // ds_read_b128

    f32x4 acc[4];
#pragma unroll
    for (int t = 0; t < 4; ++t) { acc[t][0] = 0.f; acc[t][1] = 0.f; acc[t][2] = 0.f; acc[t][3] = 0.f; }

#pragma unroll
    for (int kb = 0; kb < 4; ++kb) {
#pragma unroll
        for (int t = 0; t < 4; ++t) {
            const ushort* bp = Wt + (size_t)((tnb + t) * 16 + m16) * DIM + kb * 32 + quad * 8;
            bf16x8 bfrag = *(const bf16x8*)bp;          // global 16B, L1-resident
            acc[t] = __builtin_amdgcn_mfma_f32_16x16x32_bf16(afrag[kb], bfrag, acc[t], 0, 0, 0);
        }
    }

    // ---- bias (per col) before LN stats ----
    float gcol[4], becol[4];
#pragma unroll
    for (int t = 0; t < 4; ++t) {
        int col = (tnb + t) * 16 + m16;
        float bc = b[col];
        gcol[t]  = gamma[col];
        becol[t] = beta[col];
#pragma unroll
        for (int i = 0; i < 4; ++i) acc[t][i] += bc;
    }

    // ---- LN stats: rows 4*quad+i; reduce over this wave's 64 cols via quad shuffles ----
    float s[4], sq[4];
#pragma unroll
    for (int i = 0; i < 4; ++i) {
        s[i]  = acc[0][i] + acc[1][i] + acc[2][i] + acc[3][i];
        sq[i] = acc[0][i]*acc[0][i] + acc[1][i]*acc[1][i] + acc[2][i]*acc[2][i] + acc[3][i]*acc[3][i];
    }
#pragma unroll
    for (int off = 1; off <= 8; off <<= 1) {
#pragma unroll
        for (int i = 0; i < 4; ++i) {
            s[i]  += __shfl_xor(s[i], off);
            sq[i] += __shfl_xor(sq[i], off);
        }
    }
    if (m16 == 0) {
#pragma unroll
        for (int i = 0; i < 4; ++i) {
            redS[w][quad * 4 + i] = s[i];
            redQ[w][quad * 4 + i] = sq[i];
        }
    }
    __syncthreads();

    // ---- finish LN + GELU + residual, store ----
#pragma unroll
    for (int i = 0; i < 4; ++i) {
        int rloc = quad * 4 + i;
        float tot  = redS[w][rloc] + redS[w ^ 2][rloc];   // partner wave shares tm
        float totq = redQ[w][rloc] + redQ[w ^ 2][rloc];
        float mu   = tot * (1.0f / DIM);
        float var  = totq * (1.0f / DIM) - mu * mu;
        float rstd = rsqrtf(var + 1e-5f);
        int r = row0 + 16 * tm + rloc;
        if (r < N) {
#pragma unroll
            for (int t = 0; t < 4; ++t) {
                int col = (tnb + t) * 16 + m16;
                float l = (acc[t][i] - mu) * rstd * gcol[t] + becol[t];
                float g = 0.5f * l * (1.0f + erff(l * 0.70710678118654752f));
                out[(size_t)r * DIM + col] = x[(size_t)r * DIM + col] + g;
            }
        }
    }
}

// ---------------- fallback path (small workspace): atomic scatter + fp32 gemm_ln ----------------
__global__ void deg_kernel(const int* __restrict__ ei, const float* __restrict__ ew,
                           float* __restrict__ deg, int E) {
    int e = blockIdx.x * blockDim.x + threadIdx.x;
    if (e < E) atomicAdd(&deg[ei[E + e]], ew[e]);
}

__global__ void dinv_kernel(float* deg, int N) {
    int i = blockIdx.x * blockDim.x + threadIdx.x;
    if (i < N) {
        float d = deg[i];
        deg[i] = d > 0.f ? rsqrtf(d) : 0.f;
    }
}

__global__ void scatter_kernel(const int* __restrict__ ei, const float* __restrict__ ew,
                               const float* __restrict__ dinv, const float* __restrict__ x,
                               float* __restrict__ out, int E) {
    int t = blockIdx.x * blockDim.x + threadIdx.x;
    int e = t >> 5;
    if (e >= E) return;
    int lane = t & 31;
    int row = ei[e];
    int col = ei[E + e];
    float w = dinv[row] * ew[e] * dinv[col];
    float4 v = *(const float4*)(x + (size_t)row * DIM + (lane << 2));
    float* dst = out + (size_t)col * DIM + (lane << 2);
    atomicAdd(dst + 0, v.x * w);
    atomicAdd(dst + 1, v.y * w);
    atomicAdd(dst + 2, v.z * w);
    atomicAdd(dst + 3, v.w * w);
}

__global__ __launch_bounds__(256) void gemm_ln_kernel(const float* __restrict__ x,
                                                      const float* __restrict__ W,
                                                      const float* __restrict__ b,
                                                      const float* __restrict__ gamma,
                                                      const float* __restrict__ beta,
                                                      float* __restrict__ out, int N) {
    __shared__ float sT[DIM][TR + 4];
    const int tid = threadIdx.x;
    const int row0 = blockIdx.x * TR;
    {
        int r = tid >> 3;
        int c0 = (tid & 7) << 4;
        int rr = row0 + r; if (rr > N - 1) rr = N - 1;
        const float4* src = (const float4*)(out + (size_t)rr * DIM + c0);
#pragma unroll
        for (int i = 0; i < 4; ++i) {
            float4 v = src[i];
            int c = c0 + i * 4;
            sT[c + 0][r] = v.x; sT[c + 1][r] = v.y; sT[c + 2][r] = v.z; sT[c + 3][r] = v.w;
        }
    }
    __syncthreads();
    const int tx = tid & 31;
    const int ty = tid >> 5;
    float acc[4][4] = {};
    const float4* Wv = (const float4*)W;
#pragma unroll 4
    for (int k = 0; k < DIM; ++k) {
        float4 wv = Wv[k * 32 + tx];
        float4 a  = *(const float4*)(&sT[k][ty * 4]);
        acc[0][0] += a.x * wv.x; acc[0][1] += a.x * wv.y; acc[0][2] += a.x * wv.z; acc[0][3] += a.x * wv.w;
        acc[1][0] += a.y * wv.x; acc[1][1] += a.y * wv.y; acc[1][2] += a.y * wv.z; acc[1][3] += a.y * wv.w;
        acc[2][0] += a.z * wv.x; acc[2][1] += a.z * wv.y; acc[2][2] += a.z * wv.z; acc[2][3] += a.z * wv.w;
        acc[3][0] += a.w * wv.x; acc[3][1] += a.w * wv.y; acc[3][2] += a.w * wv.z; acc[3][3] += a.w * wv.w;
    }
    float4 b4 = ((const float4*)b)[tx];
#pragma unroll
    for (int i = 0; i < 4; ++i) {
        acc[i][0] += b4.x; acc[i][1] += b4.y; acc[i][2] += b4.z; acc[i][3] += b4.w;
    }
    float4 g4  = ((const float4*)gamma)[tx];
    float4 be4 = ((const float4*)beta)[tx];
#pragma unroll
    for (int i = 0; i < 4; ++i) {
        float s  = acc[i][0] + acc[i][1] + acc[i][2] + acc[i][3];
        float sq = acc[i][0]*acc[i][0] + acc[i][1]*acc[i][1] + acc[i][2]*acc[i][2] + acc[i][3]*acc[i][3];
#pragma unroll
        for (int off = 16; off > 0; off >>= 1) {
            s  += __shfl_xor(s, off);
            sq += __shfl_xor(sq, off);
        }
        float mu   = s * (1.0f / DIM);
        float var  = sq * (1.0f / DIM) - mu * mu;
        float rstd = rsqrtf(var + 1e-5f);
        int r = row0 + ty * 4 + i;
        if (r < N) {
            float4 xr = *(const float4*)(x + (size_t)r * DIM + tx * 4);
            float lg[4] = {g4.x, g4.y, g4.z, g4.w};
            float lb[4] = {be4.x, be4.y, be4.z, be4.w};
            float lx[4] = {xr.x, xr.y, xr.z, xr.w};
            float o[4];
#pragma unroll
            for (int c = 0; c < 4; ++c) {
                float l = (acc[i][c] - mu) * rstd * lg[c] + lb[c];
                float g = 0.5f * l * (1.0f + erff(l * 0.70710678118654752f));
                o[c] = lx[c] + g;
            }
            *(float4*)(out + (size_t)r * DIM + tx * 4) = make_float4(o[0], o[1], o[2], o[3]);
        }
    }
}

extern "C" void kernel_launch(void* const* d_in, const int* in_sizes, int n_in,
                              void* d_out, int out_size, void* d_ws, size_t ws_size,
                              hipStream_t stream) {
    const float* x     = (const float*)d_in[0];
    const int*   ei    = (const int*)d_in[1];    // [2, E] int32
    const float* ew    = (const float*)d_in[2];
    const float* W     = (const float*)d_in[3];
    const float* b     = (const float*)d_in[4];
    const float* gamma = (const float*)d_in[5];
    const float* beta  = (const float*)d_in[6];
    const int N = in_sizes[0] / DIM;
    const int E = in_sizes[2];
    float* out = (float*)d_out;

    const int nb = (N + 255) / 256;

    // ws words: Wt bf16[128*128] (8192 words) | cd u64[N] (2N) | dinv[N] |
    //           row_start[N] | cursor[N] | gctr[1] | pad | csr int2[E]
    size_t hdr_words = 8192 + (size_t)5 * N + 2;
    hdr_words = (hdr_words + 1) & ~(size_t)1;
    size_t ws_need = (hdr_words + (size_t)2 * E) * sizeof(float);

    if (ws_size >= ws_need) {
        ushort* Wt         = (ushort*)d_ws;
        unsigned long long* cd = (unsigned long long*)((float*)d_ws + 8192);
        float*  dinv       = (float*)d_ws + 8192 + (size_t)2 * N;
        int*    row_start  = (int*)(dinv + N);
        int*    cursor     = row_start + N;
        int*    gctr       = cursor + N;
        int2*   csr        = (int2*)((float*)d_ws + hdr_words);

        int initn = 16384 + 2 * N;
        init_kernel<<<(initn + 255) / 256, 256, 0, stream>>>(W, Wt, (float*)cd, 2 * N, gctr);
        count_deg_kernel<<<(E + 255) / 256, 256, 0, stream>>>(ei, ew, cd, E);
        alloc_kernel<<<nb, 256, 0, stream>>>(cd, dinv, row_start, cursor, gctr, N);
        csr_fill_kernel<<<(E + 255) / 256, 256, 0, stream>>>(ei, ew, dinv, cursor, csr, E);

        gather_mfma_ln_kernel<<<(N + TR - 1) / TR, 256, 0, stream>>>(
            csr, row_start, cursor, dinv, x, Wt, b, gamma, beta, out, N);
    } else {
        float* deg = (float*)d_ws;
        int n4 = N * DIM / 4;
        fill_zero4<<<(n4 + 255) / 256, 256, 0, stream>>>((float4*)out, n4);
        fill_zero<<<nb, 256, 0, stream>>>(deg, N);
        deg_kernel<<<(E + 255) / 256, 256, 0, stream>>>(ei, ew, deg, E);
        dinv_kernel<<<nb, 256, 0, stream>>>(deg, N);
        long long sthreads = (long long)E * 32;
        scatter_kernel<<<(int)((sthreads + 255) / 256), 256, 0, stream>>>(ei, ew, deg, x, out, E);
        gemm_ln_kernel<<<(N + TR - 1) / TR, 256, 0, stream>>>(x, W, b, gamma, beta, out, N);
    }
}

// Round 5
// 249.450 us; speedup vs baseline: 2.5283x; 1.0477x over previous
//
#include <hip/hip_runtime.h>
#include <math.h>

#define DIM 128
#define TR 32         // nodes per fused block
#define SA_STRIDE 136 // bf16 elements per sA row (128 + 8 pad, keeps 16B alignment)

#define DEG_SHIFT 42          // cnt in bits 42..63 of packed u64
#define DEG_SCALE 33554432.0f // 2^25 fixed-point scale for deg
#define DEG_MASK ((1ull << DEG_SHIFT) - 1)

typedef __attribute__((ext_vector_type(8))) short bf16x8;
typedef __attribute__((ext_vector_type(4))) float f32x4;

__device__ __forceinline__ ushort f2bf(float f) {
    union { float f; unsigned u; } v; v.f = f;
    unsigned u = v.u;
    return (ushort)((u + 0x7FFFu + ((u >> 16) & 1u)) >> 16);  // RNE
}

__global__ void fill_zero(float* p, int n) {
    int i = blockIdx.x * blockDim.x + threadIdx.x;
    if (i < n) p[i] = 0.f;
}

__global__ void fill_zero4(float4* p, int n4) {
    int i = blockIdx.x * blockDim.x + threadIdx.x;
    if (i < n4) p[i] = make_float4(0.f, 0.f, 0.f, 0.f);
}

// Fused init: Wt[n][k] = bf16(W[k][n]); zero cd (2N words); reset gctr.
__global__ void init_kernel(const float* __restrict__ W, ushort* __restrict__ Wt,
                            float* __restrict__ zbase, int nz, int* __restrict__ gctr) {
    int i = blockIdx.x * blockDim.x + threadIdx.x;
    if (i < 16384) {
        int k = i >> 7, n = i & 127;
        Wt[n * DIM + k] = f2bf(W[k * DIM + n]);
    }
    int z = i - 16384;
    if (z >= 0 && z < nz) zbase[z] = 0.f;
    if (i == 0) *gctr = 0;
}

// ONE u64 atomic per edge: cd[col] += (1<<42) | round(ew * 2^25).
// The RETURNED old value's cnt field is this edge's arrival rank within its
// node — recorded to rank[e] (coalesced write), which makes csr_fill atomic-free.
__global__ void count_deg_kernel(const int* __restrict__ ei, const float* __restrict__ ew,
                                 unsigned long long* __restrict__ cd,
                                 int* __restrict__ rank, int E) {
    int e = blockIdx.x * blockDim.x + threadIdx.x;
    if (e < E) {
        int col = ei[E + e];
        unsigned long long pk = (1ull << DEG_SHIFT)
                              + (unsigned long long)(ew[e] * DEG_SCALE + 0.5f);
        unsigned long long old = atomicAdd(&cd[col], pk);
        rank[e] = (int)(old >> DEG_SHIFT);
    }
}

// Segment allocation: wave-level inclusive scan of cnt, block-level combine in LDS,
// ONE atomicAdd per BLOCK on gctr (per-wave hot-line version serialized cross-XCD).
// Nodes within a block (256 consecutive ids) get contiguous, ordered segments.
// Writes row_start, row_end (= start + cnt) and dinv from the packed deg.
__global__ __launch_bounds__(256) void alloc_kernel(const unsigned long long* __restrict__ cd,
                                                    float* __restrict__ dinv,
                                                    int* __restrict__ row_start,
                                                    int* __restrict__ row_end,
                                                    int* __restrict__ gctr, int N) {
    __shared__ int wsum[4];
    __shared__ int sbase;
    int t = threadIdx.x;
    int i = blockIdx.x * 256 + t;
    int lane = t & 63;
    int w = t >> 6;
    unsigned long long p = (i < N) ? cd[i] : 0ull;
    int c = (int)(p >> DEG_SHIFT);
    int pre = c;
#pragma unroll
    for (int off = 1; off < 64; off <<= 1) {
        int v = __shfl_up(pre, off);
        if (lane >= off) pre += v;
    }
    if (lane == 63) wsum[w] = pre;
    __syncthreads();
    if (t == 0) sbase = atomicAdd(gctr, wsum[0] + wsum[1] + wsum[2] + wsum[3]);
    __syncthreads();
    int woff = 0;
#pragma unroll
    for (int k = 0; k < 3; ++k) if (w > k) woff += wsum[k];
    if (i < N) {
        int rs = sbase + woff + pre - c;   // exclusive prefix within block + block base
        row_start[i] = rs;
        row_end[i] = rs + c;
        float d = (float)(p & DEG_MASK) * (1.0f / DEG_SCALE);
        dinv[i] = d > 0.f ? rsqrtf(d) : 0.f;
    }
}

// CSR fill, ATOMIC-FREE: p = row_start[col] + rank[e]; csr[p] = {row, bits(ew)}.
// Per edge: one random READ (row_start[col], L2-cached — no RMW ping-pong) and
// one random 8B write. dinv[row] is applied in the gather kernel instead
// (latency-bound there = nearly free; throughput-bound here = a full line touch).
__global__ void csr_fill_kernel(const int* __restrict__ ei, const float* __restrict__ ew,
                                const int* __restrict__ rank,
                                const int* __restrict__ row_start,
                                int2* __restrict__ csr, int E) {
    int e = blockIdx.x * blockDim.x + threadIdx.x;
    if (e < E) {
        int row = ei[e];
        int col = ei[E + e];
        int p = row_start[col] + rank[e];
        csr[p] = make_int2(row, __float_as_int(ew[e]));
    }
}

// Fused: CSR gather (fp32) -> LDS bf16 -> MFMA 32x128 @ 128x128 -> bias+LN+GELU+residual.
// 256 threads = 4 waves. Gather: 8 groups of 32 lanes, 4 nodes each, ROUND-ROBIN:
// all 4 nodes' edge lists stepped in lockstep, unroll 2 -> 8 independent csr->x
// dependency chains in flight per group. unroll 4 REGRESSED (VGPR 44->72,
// occupancy 46%->30%): TLP hides more than the extra ILP adds — keep VGPR <=64.
// Per edge: csr entry -> {x row (512B), dinv[src] (4B)} issued in parallel
// (same chain depth), wt = dinv[src]*ew. Invalid slots predicated (clamp to
// csr[0], weight 0) — loads always issue, stay L1-resident.
// Final accumulator scaled by dinv[node] (factored norm).
// GEMM: wave w -> row-tile tm=w&1 (16 rows), col-tiles tn = 4*(w>>1)..+3 (64 cols).
__global__ __launch_bounds__(256) void gather_mfma_ln_kernel(
        const int2* __restrict__ csr, const int* __restrict__ row_start,
        const int* __restrict__ seg_end, const float* __restrict__ dinv,
        const float* __restrict__ x,
        const ushort* __restrict__ Wt, const float* __restrict__ b,
        const float* __restrict__ gamma, const float* __restrict__ beta,
        float* __restrict__ out, int N) {
    __shared__ ushort sA[TR * SA_STRIDE];  // 8.5 KB bf16 agg tile
    __shared__ float redS[4][16];
    __shared__ float redQ[4][16];

    const int tid  = threadIdx.x;
    const int l32  = tid & 31;
    const int g32  = tid >> 5;       // gather group 0..7
    const int lane = tid & 63;
    const int w    = tid >> 6;       // wave 0..3
    const int row0 = blockIdx.x * TR;

    // ---- Phase A: round-robin gather, 4 nodes per 32-lane group ----
    const float4* xv = (const float4*)x;
    int sidx[4], eidx[4];
    float dv[4];
    float4 accq[4];
    int maxlen = 0;
#pragma unroll
    for (int q = 0; q < 4; ++q) {
        int node = row0 + g32 * 4 + q;
        int ok = node < N;
        sidx[q] = ok ? row_start[node] : 0;
        eidx[q] = ok ? seg_end[node] : 0;
        dv[q]   = ok ? dinv[node] : 0.f;
        accq[q] = make_float4(0.f, 0.f, 0.f, 0.f);
        int len = eidx[q] - sidx[q];
        maxlen = len > maxlen ? len : maxlen;
    }
    // maxlen is group-uniform (node ids are group-uniform)
#pragma unroll 2
    for (int it = 0; it < maxlen; ++it) {
        int2 pk[4];
#pragma unroll
        for (int q = 0; q < 4; ++q) {
            int j = sidx[q] + it;
            pk[q] = csr[j < eidx[q] ? j : 0];   // predicated slot, always-valid addr
        }
        float4 v[4]; float ds[4];
#pragma unroll
        for (int q = 0; q < 4; ++q) {
            v[q]  = xv[(size_t)pk[q].x * 32 + l32];  // 512B row, parallel with...
            ds[q] = dinv[pk[q].x];                   // ...4B broadcast (same dep level)
        }
#pragma unroll
        for (int q = 0; q < 4; ++q) {
            float wt = (sidx[q] + it < eidx[q]) ? __int_as_float(pk[q].y) * ds[q] : 0.f;
            accq[q].x += wt * v[q].x; accq[q].y += wt * v[q].y;
            accq[q].z += wt * v[q].z; accq[q].w += wt * v[q].w;
        }
    }
#pragma unroll
    for (int q = 0; q < 4; ++q) {
        int r = g32 * 4 + q;
        ushort4 p4;
        p4.x = f2bf(accq[q].x * dv[q]); p4.y = f2bf(accq[q].y * dv[q]);
        p4.z = f2bf(accq[q].z * dv[q]); p4.w = f2bf(accq[q].w * dv[q]);
        *(ushort4*)&sA[r * SA_STRIDE + l32 * 4] = p4;   // ds_write_b64, conflict-free
    }
    __syncthreads();

    // ---- Phase B: MFMA GEMM ----
    const int m16  = lane & 15;
    const int quad = lane >> 4;          // 0..3
    const int tm   = w & 1;              // row-tile
    const int tnb  = (w >> 1) * 4;       // first col-tile

    bf16x8 afrag[4];
    const ushort* arow = &sA[(16 * tm + m16) * SA_STRIDE + quad * 8];
#pragma unroll
    for (int kb = 0; kb < 4; ++kb)
        afrag[kb] = *(const bf16x8*)(arow + kb * 32);   // ds_read_b128

    f32x4 acc[4];
#pragma unroll
    for (int t = 0; t < 4; ++t) { acc[t][0] = 0.f; acc[t][1] = 0.f; acc[t][2] = 0.f; acc[t][3] = 0.f; }

#pragma unroll
    for (int kb = 0; kb < 4; ++kb) {
#pragma unroll
        for (int t = 0; t < 4; ++t) {
            const ushort* bp = Wt + (size_t)((tnb + t) * 16 + m16) * DIM + kb * 32 + quad * 8;
            bf16x8 bfrag = *(const bf16x8*)bp;          // global 16B, L1-resident
            acc[t] = __builtin_amdgcn_mfma_f32_16x16x32_bf16(afrag[kb], bfrag, acc[t], 0, 0, 0);
        }
    }

    // ---- bias (per col) before LN stats ----
    float gcol[4], becol[4];
#pragma unroll
    for (int t = 0; t < 4; ++t) {
        int col = (tnb + t) * 16 + m16;
        float bc = b[col];
        gcol[t]  = gamma[col];
        becol[t] = beta[col];
#pragma unroll
        for (int i = 0; i < 4; ++i) acc[t][i] += bc;
    }

    // ---- LN stats: rows 4*quad+i; reduce over this wave's 64 cols via quad shuffles ----
    float s[4], sq[4];
#pragma unroll
    for (int i = 0; i < 4; ++i) {
        s[i]  = acc[0][i] + acc[1][i] + acc[2][i] + acc[3][i];
        sq[i] = acc[0][i]*acc[0][i] + acc[1][i]*acc[1][i] + acc[2][i]*acc[2][i] + acc[3][i]*acc[3][i];
    }
#pragma unroll
    for (int off = 1; off <= 8; off <<= 1) {
#pragma unroll
        for (int i = 0; i < 4; ++i) {
            s[i]  += __shfl_xor(s[i], off);
            sq[i] += __shfl_xor(sq[i], off);
        }
    }
    if (m16 == 0) {
#pragma unroll
        for (int i = 0; i < 4; ++i) {
            redS[w][quad * 4 + i] = s[i];
            redQ[w][quad * 4 + i] = sq[i];
        }
    }
    __syncthreads();

    // ---- finish LN + GELU + residual, store ----
#pragma unroll
    for (int i = 0; i < 4; ++i) {
        int rloc = quad * 4 + i;
        float tot  = redS[w][rloc] + redS[w ^ 2][rloc];   // partner wave shares tm
        float totq = redQ[w][rloc] + redQ[w ^ 2][rloc];
        float mu   = tot * (1.0f / DIM);
        float var  = totq * (1.0f / DIM) - mu * mu;
        float rstd = rsqrtf(var + 1e-5f);
        int r = row0 + 16 * tm + rloc;
        if (r < N) {
#pragma unroll
            for (int t = 0; t < 4; ++t) {
                int col = (tnb + t) * 16 + m16;
                float l = (acc[t][i] - mu) * rstd * gcol[t] + becol[t];
                float g = 0.5f * l * (1.0f + erff(l * 0.70710678118654752f));
                out[(size_t)r * DIM + col] = x[(size_t)r * DIM + col] + g;
            }
        }
    }
}

// ---------------- fallback path (small workspace): atomic scatter + fp32 gemm_ln ----------------
__global__ void deg_kernel(const int* __restrict__ ei, const float* __restrict__ ew,
                           float* __restrict__ deg, int E) {
    int e = blockIdx.x * blockDim.x + threadIdx.x;
    if (e < E) atomicAdd(&deg[ei[E + e]], ew[e]);
}

__global__ void dinv_kernel(float* deg, int N) {
    int i = blockIdx.x * blockDim.x + threadIdx.x;
    if (i < N) {
        float d = deg[i];
        deg[i] = d > 0.f ? rsqrtf(d) : 0.f;
    }
}

__global__ void scatter_kernel(const int* __restrict__ ei, const float* __restrict__ ew,
                               const float* __restrict__ dinv, const float* __restrict__ x,
                               float* __restrict__ out, int E) {
    int t = blockIdx.x * blockDim.x + threadIdx.x;
    int e = t >> 5;
    if (e >= E) return;
    int lane = t & 31;
    int row = ei[e];
    int col = ei[E + e];
    float w = dinv[row] * ew[e] * dinv[col];
    float4 v = *(const float4*)(x + (size_t)row * DIM + (lane << 2));
    float* dst = out + (size_t)col * DIM + (lane << 2);
    atomicAdd(dst + 0, v.x * w);
    atomicAdd(dst + 1, v.y * w);
    atomicAdd(dst + 2, v.z * w);
    atomicAdd(dst + 3, v.w * w);
}

__global__ __launch_bounds__(256) void gemm_ln_kernel(const float* __restrict__ x,
                                                      const float* __restrict__ W,
                                                      const float* __restrict__ b,
                                                      const float* __restrict__ gamma,
                                                      const float* __restrict__ beta,
                                                      float* __restrict__ out, int N) {
    __shared__ float sT[DIM][TR + 4];
    const int tid = threadIdx.x;
    const int row0 = blockIdx.x * TR;
    {
        int r = tid >> 3;
        int c0 = (tid & 7) << 4;
        int rr = row0 + r; if (rr > N - 1) rr = N - 1;
        const float4* src = (const float4*)(out + (size_t)rr * DIM + c0);
#pragma unroll
        for (int i = 0; i < 4; ++i) {
            float4 v = src[i];
            int c = c0 + i * 4;
            sT[c + 0][r] = v.x; sT[c + 1][r] = v.y; sT[c + 2][r] = v.z; sT[c + 3][r] = v.w;
        }
    }
    __syncthreads();
    const int tx = tid & 31;
    const int ty = tid >> 5;
    float acc[4][4] = {};
    const float4* Wv = (const float4*)W;
#pragma unroll 4
    for (int k = 0; k < DIM; ++k) {
        float4 wv = Wv[k * 32 + tx];
        float4 a  = *(const float4*)(&sT[k][ty * 4]);
        acc[0][0] += a.x * wv.x; acc[0][1] += a.x * wv.y; acc[0][2] += a.x * wv.z; acc[0][3] += a.x * wv.w;
        acc[1][0] += a.y * wv.x; acc[1][1] += a.y * wv.y; acc[1][2] += a.y * wv.z; acc[1][3] += a.y * wv.w;
        acc[2][0] += a.z * wv.x; acc[2][1] += a.z * wv.y; acc[2][2] += a.z * wv.z; acc[2][3] += a.z * wv.w;
        acc[3][0] += a.w * wv.x; acc[3][1] += a.w * wv.y; acc[3][2] += a.w * wv.z; acc[3][3] += a.w * wv.w;
    }
    float4 b4 = ((const float4*)b)[tx];
#pragma unroll
    for (int i = 0; i < 4; ++i) {
        acc[i][0] += b4.x; acc[i][1] += b4.y; acc[i][2] += b4.z; acc[i][3] += b4.w;
    }
    float4 g4  = ((const float4*)gamma)[tx];
    float4 be4 = ((const float4*)beta)[tx];
#pragma unroll
    for (int i = 0; i < 4; ++i) {
        float s  = acc[i][0] + acc[i][1] + acc[i][2] + acc[i][3];
        float sq = acc[i][0]*acc[i][0] + acc[i][1]*acc[i][1] + acc[i][2]*acc[i][2] + acc[i][3]*acc[i][3];
#pragma unroll
        for (int off = 16; off > 0; off >>= 1) {
            s  += __shfl_xor(s, off);
            sq += __shfl_xor(sq, off);
        }
        float mu   = s * (1.0f / DIM);
        float var  = sq * (1.0f / DIM) - mu * mu;
        float rstd = rsqrtf(var + 1e-5f);
        int r = row0 + ty * 4 + i;
        if (r < N) {
            float4 xr = *(const float4*)(x + (size_t)r * DIM + tx * 4);
            float lg[4] = {g4.x, g4.y, g4.z, g4.w};
            float lb[4] = {be4.x, be4.y, be4.z, be4.w};
            float lx[4] = {xr.x, xr.y, xr.z, xr.w};
            float o[4];
#pragma unroll
            for (int c = 0; c < 4; ++c) {
                float l = (acc[i][c] - mu) * rstd * lg[c] + lb[c];
                float g = 0.5f * l * (1.0f + erff(l * 0.70710678118654752f));
                o[c] = lx[c] + g;
            }
            *(float4*)(out + (size_t)r * DIM + tx * 4) = make_float4(o[0], o[1], o[2], o[3]);
        }
    }
}

extern "C" void kernel_launch(void* const* d_in, const int* in_sizes, int n_in,
                              void* d_out, int out_size, void* d_ws, size_t ws_size,
                              hipStream_t stream) {
    const float* x     = (const float*)d_in[0];
    const int*   ei    = (const int*)d_in[1];    // [2, E] int32
    const float* ew    = (const float*)d_in[2];
    const float* W     = (const float*)d_in[3];
    const float* b     = (const float*)d_in[4];
    const float* gamma = (const float*)d_in[5];
    const float* beta  = (const float*)d_in[6];
    const int N = in_sizes[0] / DIM;
    const int E = in_sizes[2];
    float* out = (float*)d_out;

    const int nb = (N + 255) / 256;

    // ws words: Wt bf16[128*128] (8192) | cd u64[N] (2N) | dinv[N] | row_start[N] |
    //           row_end[N] | rank[E] | gctr[1] | pad | csr int2[E]
    size_t hdr_words = 8192 + (size_t)5 * N + (size_t)E + 1;
    hdr_words = (hdr_words + 1) & ~(size_t)1;
    size_t ws_need = (hdr_words + (size_t)2 * E) * sizeof(float);

    if (ws_size >= ws_need) {
        ushort* Wt         = (ushort*)d_ws;
        unsigned long long* cd = (unsigned long long*)((float*)d_ws + 8192);
        float*  dinv       = (float*)d_ws + 8192 + (size_t)2 * N;
        int*    row_start  = (int*)(dinv + N);
        int*    row_end    = row_start + N;
        int*    rank       = row_end + N;
        int*    gctr       = rank + E;
        int2*   csr        = (int2*)((float*)d_ws + hdr_words);

        int initn = 16384 + 2 * N;
        init_kernel<<<(initn + 255) / 256, 256, 0, stream>>>(W, Wt, (float*)cd, 2 * N, gctr);
        count_deg_kernel<<<(E + 255) / 256, 256, 0, stream>>>(ei, ew, cd, rank, E);
        alloc_kernel<<<nb, 256, 0, stream>>>(cd, dinv, row_start, row_end, gctr, N);
        csr_fill_kernel<<<(E + 255) / 256, 256, 0, stream>>>(ei, ew, rank, row_start, csr, E);

        gather_mfma_ln_kernel<<<(N + TR - 1) / TR, 256, 0, stream>>>(
            csr, row_start, row_end, dinv, x, Wt, b, gamma, beta, out, N);
    } else {
        float* deg = (float*)d_ws;
        int n4 = N * DIM / 4;
        fill_zero4<<<(n4 + 255) / 256, 256, 0, stream>>>((float4*)out, n4);
        fill_zero<<<nb, 256, 0, stream>>>(deg, N);
        deg_kernel<<<(E + 255) / 256, 256, 0, stream>>>(ei, ew, deg, E);
        dinv_kernel<<<nb, 256, 0, stream>>>(deg, N);
        long long sthreads = (long long)E * 32;
        scatter_kernel<<<(int)((sthreads + 255) / 256), 256, 0, stream>>>(ei, ew, deg, x, out, E);
        gemm_ln_kernel<<<(N + TR - 1) / TR, 256, 0, stream>>>(x, W, b, gamma, beta, out, N);
    }
}

// Round 6
// 233.148 us; speedup vs baseline: 2.7051x; 1.0699x over previous
//
#include <hip/hip_runtime.h>
#include <math.h>

#define DIM 128
#define TR 32         // nodes per fused block
#define SA_STRIDE 136 // bf16 elements per sA row (128 + 8 pad, keeps 16B alignment)

#define DEG_SHIFT 42          // cnt in bits 42..63 of packed u64
#define DEG_SCALE 33554432.0f // 2^25 fixed-point scale for deg
#define DEG_MASK ((1ull << DEG_SHIFT) - 1)

typedef __attribute__((ext_vector_type(8))) short bf16x8;
typedef __attribute__((ext_vector_type(4))) float f32x4;

__device__ __forceinline__ ushort f2bf(float f) {
    union { float f; unsigned u; } v; v.f = f;
    unsigned u = v.u;
    return (ushort)((u + 0x7FFFu + ((u >> 16) & 1u)) >> 16);  // RNE
}

__global__ void fill_zero(float* p, int n) {
    int i = blockIdx.x * blockDim.x + threadIdx.x;
    if (i < n) p[i] = 0.f;
}

__global__ void fill_zero4(float4* p, int n4) {
    int i = blockIdx.x * blockDim.x + threadIdx.x;
    if (i < n4) p[i] = make_float4(0.f, 0.f, 0.f, 0.f);
}

// Fused init: Wt[n][k] = bf16(W[k][n]); zero cd (2N words); reset gctr.
__global__ void init_kernel(const float* __restrict__ W, ushort* __restrict__ Wt,
                            float* __restrict__ zbase, int nz, int* __restrict__ gctr) {
    int i = blockIdx.x * blockDim.x + threadIdx.x;
    if (i < 16384) {
        int k = i >> 7, n = i & 127;
        Wt[n * DIM + k] = f2bf(W[k * DIM + n]);
    }
    int z = i - 16384;
    if (z >= 0 && z < nz) zbase[z] = 0.f;
    if (i == 0) *gctr = 0;
}

// ONE u64 atomic per edge: cd[col] += (1<<42) | round(ew * 2^25).
// The RETURNED old value's cnt field is this edge's arrival rank within its
// node — recorded to rank[e] (coalesced write), which makes csr_fill atomic-free.
__global__ void count_deg_kernel(const int* __restrict__ ei, const float* __restrict__ ew,
                                 unsigned long long* __restrict__ cd,
                                 int* __restrict__ rank, int E) {
    int e = blockIdx.x * blockDim.x + threadIdx.x;
    if (e < E) {
        int col = ei[E + e];
        unsigned long long pk = (1ull << DEG_SHIFT)
                              + (unsigned long long)(ew[e] * DEG_SCALE + 0.5f);
        unsigned long long old = atomicAdd(&cd[col], pk);
        rank[e] = (int)(old >> DEG_SHIFT);
    }
}

// Segment allocation: wave-level inclusive scan of cnt, block-level combine in LDS,
// ONE atomicAdd per BLOCK on gctr (per-wave hot-line version serialized cross-XCD).
// Nodes within a block (256 consecutive ids) get contiguous, ordered segments.
// Writes row_start, row_end (= start + cnt) and dinv from the packed deg.
__global__ __launch_bounds__(256) void alloc_kernel(const unsigned long long* __restrict__ cd,
                                                    float* __restrict__ dinv,
                                                    int* __restrict__ row_start,
                                                    int* __restrict__ row_end,
                                                    int* __restrict__ gctr, int N) {
    __shared__ int wsum[4];
    __shared__ int sbase;
    int t = threadIdx.x;
    int i = blockIdx.x * 256 + t;
    int lane = t & 63;
    int w = t >> 6;
    unsigned long long p = (i < N) ? cd[i] : 0ull;
    int c = (int)(p >> DEG_SHIFT);
    int pre = c;
#pragma unroll
    for (int off = 1; off < 64; off <<= 1) {
        int v = __shfl_up(pre, off);
        if (lane >= off) pre += v;
    }
    if (lane == 63) wsum[w] = pre;
    __syncthreads();
    if (t == 0) sbase = atomicAdd(gctr, wsum[0] + wsum[1] + wsum[2] + wsum[3]);
    __syncthreads();
    int woff = 0;
#pragma unroll
    for (int k = 0; k < 3; ++k) if (w > k) woff += wsum[k];
    if (i < N) {
        int rs = sbase + woff + pre - c;   // exclusive prefix within block + block base
        row_start[i] = rs;
        row_end[i] = rs + c;
        float d = (float)(p & DEG_MASK) * (1.0f / DEG_SCALE);
        dinv[i] = d > 0.f ? rsqrtf(d) : 0.f;
    }
}

// CSR fill, ATOMIC-FREE: p = row_start[col] + rank[e]; csr[p] = {row, bits(dinv[row]*ew)}.
// Per edge: two random READS (row_start[col], dinv[row] — no RMW ping-pong) and one
// random 8B write. The dinv[row] product lives HERE, not in the gather: round 5
// proved the per-edge dinv load in the gather costs ~20 us (load-queue pressure,
// occupancy 46->38%), while here it's one extra L2-cached read in a
// throughput-bound pass (~+6 us). Net win.
__global__ void csr_fill_kernel(const int* __restrict__ ei, const float* __restrict__ ew,
                                const int* __restrict__ rank,
                                const int* __restrict__ row_start,
                                const float* __restrict__ dinv,
                                int2* __restrict__ csr, int E) {
    int e = blockIdx.x * blockDim.x + threadIdx.x;
    if (e < E) {
        int row = ei[e];
        int col = ei[E + e];
        int p = row_start[col] + rank[e];
        float w = dinv[row] * ew[e];
        csr[p] = make_int2(row, __float_as_int(w));
    }
}

// Fused: CSR gather (fp32) -> LDS bf16 -> MFMA 32x128 @ 128x128 -> bias+LN+GELU+residual.
// 256 threads = 4 waves. Gather: 8 groups of 32 lanes, 4 nodes each, ROUND-ROBIN:
// all 4 nodes' edge lists stepped in lockstep, unroll 2 -> 8 independent csr->x
// dependency chains in flight per group. unroll 4 REGRESSED (VGPR 72, occupancy
// 30%); per-edge dinv load REGRESSED (VGPR 56, occupancy 38%): keep exactly ONE
// x-row load per edge chain and VGPR <=48. Invalid slots predicated (clamp to
// csr[0], weight 0) — loads always issue, stay L1-resident.
// Final accumulator scaled by dinv[node] (factored norm).
// GEMM: wave w -> row-tile tm=w&1 (16 rows), col-tiles tn = 4*(w>>1)..+3 (64 cols).
__global__ __launch_bounds__(256) void gather_mfma_ln_kernel(
        const int2* __restrict__ csr, const int* __restrict__ row_start,
        const int* __restrict__ seg_end, const float* __restrict__ dinv,
        const float* __restrict__ x,
        const ushort* __restrict__ Wt, const float* __restrict__ b,
        const float* __restrict__ gamma, const float* __restrict__ beta,
        float* __restrict__ out, int N) {
    __shared__ ushort sA[TR * SA_STRIDE];  // 8.5 KB bf16 agg tile
    __shared__ float redS[4][16];
    __shared__ float redQ[4][16];

    const int tid  = threadIdx.x;
    const int l32  = tid & 31;
    const int g32  = tid >> 5;       // gather group 0..7
    const int lane = tid & 63;
    const int w    = tid >> 6;       // wave 0..3
    const int row0 = blockIdx.x * TR;

    // ---- Phase A: round-robin gather, 4 nodes per 32-lane group ----
    const float4* xv = (const float4*)x;
    int sidx[4], eidx[4];
    float dv[4];
    float4 accq[4];
    int maxlen = 0;
#pragma unroll
    for (int q = 0; q < 4; ++q) {
        int node = row0 + g32 * 4 + q;
        int ok = node < N;
        sidx[q] = ok ? row_start[node] : 0;
        eidx[q] = ok ? seg_end[node] : 0;
        dv[q]   = ok ? dinv[node] : 0.f;
        accq[q] = make_float4(0.f, 0.f, 0.f, 0.f);
        int len = eidx[q] - sidx[q];
        maxlen = len > maxlen ? len : maxlen;
    }
    // maxlen is group-uniform (node ids are group-uniform)
#pragma unroll 2
    for (int it = 0; it < maxlen; ++it) {
        int2 pk[4];
#pragma unroll
        for (int q = 0; q < 4; ++q) {
            int j = sidx[q] + it;
            pk[q] = csr[j < eidx[q] ? j : 0];   // predicated slot, always-valid addr
        }
#pragma unroll
        for (int q = 0; q < 4; ++q) {
            float wt = (sidx[q] + it < eidx[q]) ? __int_as_float(pk[q].y) : 0.f;
            float4 v = xv[(size_t)pk[q].x * 32 + l32];
            accq[q].x += wt * v.x; accq[q].y += wt * v.y;
            accq[q].z += wt * v.z; accq[q].w += wt * v.w;
        }
    }
#pragma unroll
    for (int q = 0; q < 4; ++q) {
        int r = g32 * 4 + q;
        ushort4 p4;
        p4.x = f2bf(accq[q].x * dv[q]); p4.y = f2bf(accq[q].y * dv[q]);
        p4.z = f2bf(accq[q].z * dv[q]); p4.w = f2bf(accq[q].w * dv[q]);
        *(ushort4*)&sA[r * SA_STRIDE + l32 * 4] = p4;   // ds_write_b64, conflict-free
    }
    __syncthreads();

    // ---- Phase B: MFMA GEMM ----
    const int m16  = lane & 15;
    const int quad = lane >> 4;          // 0..3
    const int tm   = w & 1;              // row-tile
    const int tnb  = (w >> 1) * 4;       // first col-tile

    bf16x8 afrag[4];
    const ushort* arow = &sA[(16 * tm + m16) * SA_STRIDE + quad * 8];
#pragma unroll
    for (int kb = 0; kb < 4; ++kb)
        afrag[kb] = *(const bf16x8*)(arow + kb * 32);   // ds_read_b128

    f32x4 acc[4];
#pragma unroll
    for (int t = 0; t < 4; ++t) { acc[t][0] = 0.f; acc[t][1] = 0.f; acc[t][2] = 0.f; acc[t][3] = 0.f; }

#pragma unroll
    for (int kb = 0; kb < 4; ++kb) {
#pragma unroll
        for (int t = 0; t < 4; ++t) {
            const ushort* bp = Wt + (size_t)((tnb + t) * 16 + m16) * DIM + kb * 32 + quad * 8;
            bf16x8 bfrag = *(const bf16x8*)bp;          // global 16B, L1-resident
            acc[t] = __builtin_amdgcn_mfma_f32_16x16x32_bf16(afrag[kb], bfrag, acc[t], 0, 0, 0);
        }
    }

    // ---- bias (per col) before LN stats ----
    float gcol[4], becol[4];
#pragma unroll
    for (int t = 0; t < 4; ++t) {
        int col = (tnb + t) * 16 + m16;
        float bc = b[col];
        gcol[t]  = gamma[col];
        becol[t] = beta[col];
#pragma unroll
        for (int i = 0; i < 4; ++i) acc[t][i] += bc;
    }

    // ---- LN stats: rows 4*quad+i; reduce over this wave's 64 cols via quad shuffles ----
    float s[4], sq[4];
#pragma unroll
    for (int i = 0; i < 4; ++i) {
        s[i]  = acc[0][i] + acc[1][i] + acc[2][i] + acc[3][i];
        sq[i] = acc[0][i]*acc[0][i] + acc[1][i]*acc[1][i] + acc[2][i]*acc[2][i] + acc[3][i]*acc[3][i];
    }
#pragma unroll
    for (int off = 1; off <= 8; off <<= 1) {
#pragma unroll
        for (int i = 0; i < 4; ++i) {
            s[i]  += __shfl_xor(s[i], off);
            sq[i] += __shfl_xor(sq[i], off);
        }
    }
    if (m16 == 0) {
#pragma unroll
        for (int i = 0; i < 4; ++i) {
            redS[w][quad * 4 + i] = s[i];
            redQ[w][quad * 4 + i] = sq[i];
        }
    }
    __syncthreads();

    // ---- finish LN + GELU + residual, store ----
#pragma unroll
    for (int i = 0; i < 4; ++i) {
        int rloc = quad * 4 + i;
        float tot  = redS[w][rloc] + redS[w ^ 2][rloc];   // partner wave shares tm
        float totq = redQ[w][rloc] + redQ[w ^ 2][rloc];
        float mu   = tot * (1.0f / DIM);
        float var  = totq * (1.0f / DIM) - mu * mu;
        float rstd = rsqrtf(var + 1e-5f);
        int r = row0 + 16 * tm + rloc;
        if (r < N) {
#pragma unroll
            for (int t = 0; t < 4; ++t) {
                int col = (tnb + t) * 16 + m16;
                float l = (acc[t][i] - mu) * rstd * gcol[t] + becol[t];
                float g = 0.5f * l * (1.0f + erff(l * 0.70710678118654752f));
                out[(size_t)r * DIM + col] = x[(size_t)r * DIM + col] + g;
            }
        }
    }
}

// ---------------- fallback path (small workspace): atomic scatter + fp32 gemm_ln ----------------
__global__ void deg_kernel(const int* __restrict__ ei, const float* __restrict__ ew,
                           float* __restrict__ deg, int E) {
    int e = blockIdx.x * blockDim.x + threadIdx.x;
    if (e < E) atomicAdd(&deg[ei[E + e]], ew[e]);
}

__global__ void dinv_kernel(float* deg, int N) {
    int i = blockIdx.x * blockDim.x + threadIdx.x;
    if (i < N) {
        float d = deg[i];
        deg[i] = d > 0.f ? rsqrtf(d) : 0.f;
    }
}

__global__ void scatter_kernel(const int* __restrict__ ei, const float* __restrict__ ew,
                               const float* __restrict__ dinv, const float* __restrict__ x,
                               float* __restrict__ out, int E) {
    int t = blockIdx.x * blockDim.x + threadIdx.x;
    int e = t >> 5;
    if (e >= E) return;
    int lane = t & 31;
    int row = ei[e];
    int col = ei[E + e];
    float w = dinv[row] * ew[e] * dinv[col];
    float4 v = *(const float4*)(x + (size_t)row * DIM + (lane << 2));
    float* dst = out + (size_t)col * DIM + (lane << 2);
    atomicAdd(dst + 0, v.x * w);
    atomicAdd(dst + 1, v.y * w);
    atomicAdd(dst + 2, v.z * w);
    atomicAdd(dst + 3, v.w * w);
}

__global__ __launch_bounds__(256) void gemm_ln_kernel(const float* __restrict__ x,
                                                      const float* __restrict__ W,
                                                      const float* __restrict__ b,
                                                      const float* __restrict__ gamma,
                                                      const float* __restrict__ beta,
                                                      float* __restrict__ out, int N) {
    __shared__ float sT[DIM][TR + 4];
    const int tid = threadIdx.x;
    const int row0 = blockIdx.x * TR;
    {
        int r = tid >> 3;
        int c0 = (tid & 7) << 4;
        int rr = row0 + r; if (rr > N - 1) rr = N - 1;
        const float4* src = (const float4*)(out + (size_t)rr * DIM + c0);
#pragma unroll
        for (int i = 0; i < 4; ++i) {
            float4 v = src[i];
            int c = c0 + i * 4;
            sT[c + 0][r] = v.x; sT[c + 1][r] = v.y; sT[c + 2][r] = v.z; sT[c + 3][r] = v.w;
        }
    }
    __syncthreads();
    const int tx = tid & 31;
    const int ty = tid >> 5;
    float acc[4][4] = {};
    const float4* Wv = (const float4*)W;
#pragma unroll 4
    for (int k = 0; k < DIM; ++k) {
        float4 wv = Wv[k * 32 + tx];
        float4 a  = *(const float4*)(&sT[k][ty * 4]);
        acc[0][0] += a.x * wv.x; acc[0][1] += a.x * wv.y; acc[0][2] += a.x * wv.z; acc[0][3] += a.x * wv.w;
        acc[1][0] += a.y * wv.x; acc[1][1] += a.y * wv.y; acc[1][2] += a.y * wv.z; acc[1][3] += a.y * wv.w;
        acc[2][0] += a.z * wv.x; acc[2][1] += a.z * wv.y; acc[2][2] += a.z * wv.z; acc[2][3] += a.z * wv.w;
        acc[3][0] += a.w * wv.x; acc[3][1] += a.w * wv.y; acc[3][2] += a.w * wv.z; acc[3][3] += a.w * wv.w;
    }
    float4 b4 = ((const float4*)b)[tx];
#pragma unroll
    for (int i = 0; i < 4; ++i) {
        acc[i][0] += b4.x; acc[i][1] += b4.y; acc[i][2] += b4.z; acc[i][3] += b4.w;
    }
    float4 g4  = ((const float4*)gamma)[tx];
    float4 be4 = ((const float4*)beta)[tx];
#pragma unroll
    for (int i = 0; i < 4; ++i) {
        float s  = acc[i][0] + acc[i][1] + acc[i][2] + acc[i][3];
        float sq = acc[i][0]*acc[i][0] + acc[i][1]*acc[i][1] + acc[i][2]*acc[i][2] + acc[i][3]*acc[i][3];
#pragma unroll
        for (int off = 16; off > 0; off >>= 1) {
            s  += __shfl_xor(s, off);
            sq += __shfl_xor(sq, off);
        }
        float mu   = s * (1.0f / DIM);
        float var  = sq * (1.0f / DIM) - mu * mu;
        float rstd = rsqrtf(var + 1e-5f);
        int r = row0 + ty * 4 + i;
        if (r < N) {
            float4 xr = *(const float4*)(x + (size_t)r * DIM + tx * 4);
            float lg[4] = {g4.x, g4.y, g4.z, g4.w};
            float lb[4] = {be4.x, be4.y, be4.z, be4.w};
            float lx[4] = {xr.x, xr.y, xr.z, xr.w};
            float o[4];
#pragma unroll
            for (int c = 0; c < 4; ++c) {
                float l = (acc[i][c] - mu) * rstd * lg[c] + lb[c];
                float g = 0.5f * l * (1.0f + erff(l * 0.70710678118654752f));
                o[c] = lx[c] + g;
            }
            *(float4*)(out + (size_t)r * DIM + tx * 4) = make_float4(o[0], o[1], o[2], o[3]);
        }
    }
}

extern "C" void kernel_launch(void* const* d_in, const int* in_sizes, int n_in,
                              void* d_out, int out_size, void* d_ws, size_t ws_size,
                              hipStream_t stream) {
    const float* x     = (const float*)d_in[0];
    const int*   ei    = (const int*)d_in[1];    // [2, E] int32
    const float* ew    = (const float*)d_in[2];
    const float* W     = (const float*)d_in[3];
    const float* b     = (const float*)d_in[4];
    const float* gamma = (const float*)d_in[5];
    const float* beta  = (const float*)d_in[6];
    const int N = in_sizes[0] / DIM;
    const int E = in_sizes[2];
    float* out = (float*)d_out;

    const int nb = (N + 255) / 256;

    // ws words: Wt bf16[128*128] (8192) | cd u64[N] (2N) | dinv[N] | row_start[N] |
    //           row_end[N] | rank[E] | gctr[1] | pad | csr int2[E]
    size_t hdr_words = 8192 + (size_t)5 * N + (size_t)E + 1;
    hdr_words = (hdr_words + 1) & ~(size_t)1;
    size_t ws_need = (hdr_words + (size_t)2 * E) * sizeof(float);

    if (ws_size >= ws_need) {
        ushort* Wt         = (ushort*)d_ws;
        unsigned long long* cd = (unsigned long long*)((float*)d_ws + 8192);
        float*  dinv       = (float*)d_ws + 8192 + (size_t)2 * N;
        int*    row_start  = (int*)(dinv + N);
        int*    row_end    = row_start + N;
        int*    rank       = row_end + N;
        int*    gctr       = rank + E;
        int2*   csr        = (int2*)((float*)d_ws + hdr_words);

        int initn = 16384 + 2 * N;
        init_kernel<<<(initn + 255) / 256, 256, 0, stream>>>(W, Wt, (float*)cd, 2 * N, gctr);
        count_deg_kernel<<<(E + 255) / 256, 256, 0, stream>>>(ei, ew, cd, rank, E);
        alloc_kernel<<<nb, 256, 0, stream>>>(cd, dinv, row_start, row_end, gctr, N);
        csr_fill_kernel<<<(E + 255) / 256, 256, 0, stream>>>(ei, ew, rank, row_start, dinv, csr, E);

        gather_mfma_ln_kernel<<<(N + TR - 1) / TR, 256, 0, stream>>>(
            csr, row_start, row_end, dinv, x, Wt, b, gamma, beta, out, N);
    } else {
        float* deg = (float*)d_ws;
        int n4 = N * DIM / 4;
        fill_zero4<<<(n4 + 255) / 256, 256, 0, stream>>>((float4*)out, n4);
        fill_zero<<<nb, 256, 0, stream>>>(deg, N);
        deg_kernel<<<(E + 255) / 256, 256, 0, stream>>>(ei, ew, deg, E);
        dinv_kernel<<<nb, 256, 0, stream>>>(deg, N);
        long long sthreads = (long long)E * 32;
        scatter_kernel<<<(int)((sthreads + 255) / 256), 256, 0, stream>>>(ei, ew, deg, x, out, E);
        gemm_ln_kernel<<<(N + TR - 1) / TR, 256, 0, stream>>>(x, W, b, gamma, beta, out, N);
    }
}